// Round 1
// baseline (2100.490 us; speedup 1.0000x reference)
//
#include <hip/hip_runtime.h>
#include <hip/hip_bf16.h>
#include <math.h>

#define B_ 16
#define C_ 512
#define N_ 4096
#define NCOL (B_ * N_)  // 65536 columns (b, hw)

// ---------------------------------------------------------------------------
// K1/K8: per-column L2 norm over the 512 channels -> rs = sqrt(512)/max(||x||,eps)
// layout X[b][c][n]; one thread per column (b,n); coalesced across n.
// ---------------------------------------------------------------------------
__global__ __launch_bounds__(256) void colnorm_k(const float* __restrict__ X,
                                                 float* __restrict__ rs)
{
    int col = blockIdx.x * 256 + threadIdx.x;   // 0..65535
    int b = col >> 12, n = col & 4095;
    const float* p = X + ((size_t)b * C_) * N_ + n;
    float s = 0.f;
    #pragma unroll 8
    for (int c = 0; c < C_; ++c) {
        float v = p[(size_t)c * N_];
        s += v * v;
    }
    rs[col] = 22.627416998f / fmaxf(sqrtf(s), 1e-12f);  // sqrt(512)/norm
}

// ---------------------------------------------------------------------------
// GEMM: C[b][o][n] = sum_c A[o][c]*(g[c] if MODE==0) * X[b][c][n]
// MODE 0 (QKV): epilogue *= colscale[b*4096+n], routed to q/k/v by o>>9
// MODE 1 (OUT): epilogue += bias[o], single destination
// 128x128 tile, 256 threads, 8x8 microtile, BK=8. All dims divide exactly.
// ---------------------------------------------------------------------------
template <int MODE>
__global__ __launch_bounds__(256)
void gemm_k(const float* __restrict__ A, const float* __restrict__ gvec,
            const float* __restrict__ X, const float* __restrict__ colscale,
            const float* __restrict__ bias,
            float* __restrict__ d0, float* __restrict__ d1, float* __restrict__ d2)
{
    constexpr int K = 512;
    const int b  = blockIdx.z;
    const int m0 = blockIdx.y * 128;
    const int n0 = blockIdx.x * 128;
    const float* Xb = X + (size_t)b * K * N_;

    __shared__ __align__(16) float As[8][128];  // transposed: As[k][row]
    __shared__ __align__(16) float Bs[8][128];

    const int tid = threadIdx.x;
    const int ty = tid >> 4, tx = tid & 15;

    const int arow = tid >> 1;         // 0..127
    const int ak   = (tid & 1) * 4;    // 0 or 4
    const int bk   = tid >> 5;         // 0..7
    const int bcol = (tid & 31) * 4;   // 0..124

    float acc[8][8] = {};

    for (int k0 = 0; k0 < K; k0 += 8) {
        float4 av = *reinterpret_cast<const float4*>(A + (size_t)(m0 + arow) * K + k0 + ak);
        if constexpr (MODE == 0) {
            float4 gv = *reinterpret_cast<const float4*>(gvec + k0 + ak);
            av.x *= gv.x; av.y *= gv.y; av.z *= gv.z; av.w *= gv.w;
        }
        As[ak + 0][arow] = av.x;
        As[ak + 1][arow] = av.y;
        As[ak + 2][arow] = av.z;
        As[ak + 3][arow] = av.w;
        float4 bv = *reinterpret_cast<const float4*>(Xb + (size_t)(k0 + bk) * N_ + n0 + bcol);
        *reinterpret_cast<float4*>(&Bs[bk][bcol]) = bv;
        __syncthreads();
        #pragma unroll
        for (int kk = 0; kk < 8; ++kk) {
            float a[8], bb[8];
            *(float4*)&a[0]  = *(float4*)&As[kk][ty * 8];
            *(float4*)&a[4]  = *(float4*)&As[kk][ty * 8 + 4];
            *(float4*)&bb[0] = *(float4*)&Bs[kk][tx * 8];
            *(float4*)&bb[4] = *(float4*)&Bs[kk][tx * 8 + 4];
            #pragma unroll
            for (int i = 0; i < 8; ++i)
                #pragma unroll
                for (int j = 0; j < 8; ++j)
                    acc[i][j] = fmaf(a[i], bb[j], acc[i][j]);
        }
        __syncthreads();
    }

    const int nb = n0 + tx * 8;
    if constexpr (MODE == 0) {
        float sc[8];
        #pragma unroll
        for (int j = 0; j < 8; ++j) sc[j] = colscale[(size_t)b * N_ + nb + j];
        #pragma unroll
        for (int i = 0; i < 8; ++i) {
            int o = m0 + ty * 8 + i;
            int part = o >> 9, ol = o & 511;
            float* dst = (part == 0) ? d0 : (part == 1 ? d1 : d2);
            float* pp = dst + ((size_t)b * 512 + ol) * N_ + nb;
            float4 w0 = make_float4(acc[i][0]*sc[0], acc[i][1]*sc[1], acc[i][2]*sc[2], acc[i][3]*sc[3]);
            float4 w1 = make_float4(acc[i][4]*sc[4], acc[i][5]*sc[5], acc[i][6]*sc[6], acc[i][7]*sc[7]);
            *reinterpret_cast<float4*>(pp)     = w0;
            *reinterpret_cast<float4*>(pp + 4) = w1;
        }
    } else {
        #pragma unroll
        for (int i = 0; i < 8; ++i) {
            int o = m0 + ty * 8 + i;
            float bo = bias[o];
            float* pp = d0 + ((size_t)b * 512 + o) * N_ + nb;
            float4 w0 = make_float4(acc[i][0]+bo, acc[i][1]+bo, acc[i][2]+bo, acc[i][3]+bo);
            float4 w1 = make_float4(acc[i][4]+bo, acc[i][5]+bo, acc[i][6]+bo, acc[i][7]+bo);
            *reinterpret_cast<float4*>(pp)     = w0;
            *reinterpret_cast<float4*>(pp + 4) = w1;
        }
    }
}

// ---------------------------------------------------------------------------
// K3: softmax over d (64, stride 4096) per (b,h,n), then *SCALE (=0.125).
// q lives in d_out as (b*8+h, 64, 4096). One thread per (b,h,n).
// ---------------------------------------------------------------------------
__global__ __launch_bounds__(256) void softmax_d_k(float* __restrict__ q)
{
    int idx = blockIdx.x * 256 + threadIdx.x;   // b*h*n = 524288
    int n = idx & 4095, bh = idx >> 12;
    float* p = q + (size_t)bh * 64 * N_ + n;
    float vals[64];
    float m = -1e30f;
    #pragma unroll
    for (int d = 0; d < 64; ++d) { vals[d] = p[(size_t)d * N_]; m = fmaxf(m, vals[d]); }
    float s = 0.f;
    #pragma unroll
    for (int d = 0; d < 64; ++d) { vals[d] = expf(vals[d] - m); s += vals[d]; }
    float r = 0.125f / s;
    #pragma unroll
    for (int d = 0; d < 64; ++d) p[(size_t)d * N_] = vals[d] * r;
}

// ---------------------------------------------------------------------------
// K4: softmax over n (4096, contiguous) per (b,h,d) row. One block per row.
// ---------------------------------------------------------------------------
__global__ __launch_bounds__(256) void softmax_n_k(float* __restrict__ kk)
{
    float* p = kk + (size_t)blockIdx.x * N_;
    const int tid = threadIdx.x;
    float v[16];
    float m = -1e30f;
    #pragma unroll
    for (int i = 0; i < 16; ++i) { v[i] = p[tid + i * 256]; m = fmaxf(m, v[i]); }
    #pragma unroll
    for (int o = 32; o >= 1; o >>= 1) m = fmaxf(m, __shfl_xor(m, o));
    __shared__ float red[4];
    const int wid = tid >> 6, lane = tid & 63;
    if (lane == 0) red[wid] = m;
    __syncthreads();
    m = fmaxf(fmaxf(red[0], red[1]), fmaxf(red[2], red[3]));
    float s = 0.f;
    #pragma unroll
    for (int i = 0; i < 16; ++i) { v[i] = expf(v[i] - m); s += v[i]; }
    #pragma unroll
    for (int o = 32; o >= 1; o >>= 1) s += __shfl_xor(s, o);
    __syncthreads();
    if (lane == 0) red[wid] = s;
    __syncthreads();
    s = red[0] + red[1] + red[2] + red[3];
    float r = 1.f / s;
    #pragma unroll
    for (int i = 0; i < 16; ++i) p[tid + i * 256] = v[i] * r;
}

// ---------------------------------------------------------------------------
// K5: context[bh][d][e] = sum_n k[bh][d][n] * v[bh][e][n].  One block per bh.
// LDS tiles 64x128 (padded to 129 -> conflict-free), 4x4 microtile/thread.
// ---------------------------------------------------------------------------
__global__ __launch_bounds__(256) void ctx_k(const float* __restrict__ kk,
                                             const float* __restrict__ vv,
                                             float* __restrict__ ctx)
{
    const int bh = blockIdx.x;
    const float* kp = kk + (size_t)bh * 64 * N_;
    const float* vp = vv + (size_t)bh * 64 * N_;
    __shared__ float ks[64][129];
    __shared__ float vs[64][129];
    const int tid = threadIdx.x;
    const int td = tid >> 4, te = tid & 15;
    float acc[4][4] = {};
    for (int n0 = 0; n0 < N_; n0 += 128) {
        #pragma unroll
        for (int i = 0; i < 32; ++i) {
            int idx = i * 256 + tid;          // 0..8191
            int d = idx >> 7, nn = idx & 127;
            ks[d][nn] = kp[(size_t)d * N_ + n0 + nn];
            vs[d][nn] = vp[(size_t)d * N_ + n0 + nn];
        }
        __syncthreads();
        for (int nn = 0; nn < 128; ++nn) {
            float a[4], bb[4];
            #pragma unroll
            for (int i = 0; i < 4; ++i) a[i]  = ks[td * 4 + i][nn];
            #pragma unroll
            for (int j = 0; j < 4; ++j) bb[j] = vs[te * 4 + j][nn];
            #pragma unroll
            for (int i = 0; i < 4; ++i)
                #pragma unroll
                for (int j = 0; j < 4; ++j)
                    acc[i][j] = fmaf(a[i], bb[j], acc[i][j]);
        }
        __syncthreads();
    }
    #pragma unroll
    for (int i = 0; i < 4; ++i)
        #pragma unroll
        for (int j = 0; j < 4; ++j)
            ctx[(size_t)bh * 4096 + (td * 4 + i) * 64 + (te * 4 + j)] = acc[i][j];
}

// ---------------------------------------------------------------------------
// K6: out[bh][e][n] = sum_d ctx[bh][d][e] * q[bh][d][n], n-tile = 256.
// q read from d_out, result written to kbuf (k is dead). 16e x 4n per thread.
// ---------------------------------------------------------------------------
__global__ __launch_bounds__(256) void attn_k(const float* __restrict__ ctx,
                                              const float* __restrict__ q,
                                              float* __restrict__ out)
{
    const int bh = blockIdx.y;          // 0..127
    const int n0 = blockIdx.x * 256;
    __shared__ __align__(16) float ctx_s[64][64];
    __shared__ __align__(16) float q_s[64][256];
    const float* cp = ctx + (size_t)bh * 4096;
    const float* qp = q + (size_t)bh * 64 * N_;
    const int tid = threadIdx.x;
    #pragma unroll
    for (int i = 0; i < 16; ++i) {
        int idx = i * 256 + tid;
        ctx_s[idx >> 6][idx & 63] = cp[idx];
    }
    #pragma unroll 4
    for (int d = 0; d < 64; ++d)
        q_s[d][tid] = qp[(size_t)d * N_ + n0 + tid];
    __syncthreads();
    const int eg = tid >> 6;      // e base = eg*16
    const int ng = tid & 63;      // n base = ng*4
    float acc[16][4] = {};
    for (int d = 0; d < 64; ++d) {
        float qv[4];
        *(float4*)qv = *(float4*)&q_s[d][ng * 4];
        float cvals[16];
        #pragma unroll
        for (int t = 0; t < 4; ++t)
            *(float4*)&cvals[t * 4] = *(float4*)&ctx_s[d][eg * 16 + t * 4];
        #pragma unroll
        for (int e = 0; e < 16; ++e)
            #pragma unroll
            for (int j = 0; j < 4; ++j)
                acc[e][j] = fmaf(cvals[e], qv[j], acc[e][j]);
    }
    float* op = out + (size_t)bh * 64 * N_ + n0 + ng * 4;
    #pragma unroll
    for (int e = 0; e < 16; ++e) {
        float4 w = make_float4(acc[e][0], acc[e][1], acc[e][2], acc[e][3]);
        *reinterpret_cast<float4*>(op + (size_t)(eg * 16 + e) * N_) = w;
    }
}

// ---------------------------------------------------------------------------
// K9: d_out[b][o][n] *= rs2[b*4096+n] * g2[o]   (final rms-norm apply)
// ---------------------------------------------------------------------------
__global__ __launch_bounds__(256) void scale_k(float* __restrict__ out,
                                               const float* __restrict__ rs,
                                               const float* __restrict__ g2)
{
    size_t f = (size_t)blockIdx.x * 256 + threadIdx.x;   // 8388608 float4s
    size_t e = f * 4;
    int o = (int)((e >> 12) & 511);
    int b = (int)(e >> 21);
    int n = (int)(e & 4095);
    float4 v = reinterpret_cast<float4*>(out)[f];
    float4 s = *reinterpret_cast<const float4*>(&rs[(size_t)b * 4096 + n]);
    float g = g2[o];
    v.x *= s.x * g; v.y *= s.y * g; v.z *= s.z * g; v.w *= s.w * g;
    reinterpret_cast<float4*>(out)[f] = v;
}

// ---------------------------------------------------------------------------
extern "C" void kernel_launch(void* const* d_in, const int* in_sizes, int n_in,
                              void* d_out, int out_size, void* d_ws, size_t ws_size,
                              hipStream_t stream)
{
    const float* x    = (const float*)d_in[0];
    const float* g1   = (const float*)d_in[1];
    const float* Wqkv = (const float*)d_in[2];
    const float* Wout = (const float*)d_in[3];
    const float* bout = (const float*)d_in[4];
    const float* g2   = (const float*)d_in[5];
    float* out = (float*)d_out;

    // workspace layout (floats): k[128Mi B], v[128Mi B], ctx[2MiB], rs1, rs2
    float* ws   = (float*)d_ws;
    float* kbuf = ws;
    float* vbuf = kbuf + (size_t)B_ * C_ * N_;
    float* ctxb = vbuf + (size_t)B_ * C_ * N_;
    float* rs1  = ctxb + (size_t)128 * 64 * 64;
    float* rs2  = rs1 + NCOL;

    // 1. column norms of x (rms-norm folded into GEMM1 epilogue)
    colnorm_k<<<NCOL / 256, 256, 0, stream>>>(x, rs1);
    // 2. QKV GEMM: q -> d_out (scratch until GEMM2), k -> kbuf, v -> vbuf
    gemm_k<0><<<dim3(32, 12, B_), 256, 0, stream>>>(Wqkv, g1, x, rs1, nullptr,
                                                    out, kbuf, vbuf);
    // 3. softmax over d on q (in place, in d_out)
    softmax_d_k<<<(B_ * 8 * N_) / 256, 256, 0, stream>>>(out);
    // 4. softmax over n on k (in place)
    softmax_n_k<<<B_ * 8 * 64, 256, 0, stream>>>(kbuf);
    // 5. context = k @ v^T per (b,h)
    ctx_k<<<B_ * 8, 256, 0, stream>>>(kbuf, vbuf, ctxb);
    // 6. attn = ctx^T @ q per (b,h), overwrites kbuf (k is dead)
    attn_k<<<dim3(N_ / 256, B_ * 8), 256, 0, stream>>>(ctxb, out, kbuf);
    // 7. output GEMM + bias -> d_out (q is dead)
    gemm_k<1><<<dim3(32, 4, B_), 256, 0, stream>>>(Wout, nullptr, kbuf, nullptr,
                                                   bout, out, nullptr, nullptr);
    // 8-9. final rms-norm: column norms then in-place scale
    colnorm_k<<<NCOL / 256, 256, 0, stream>>>(out, rs2);
    scale_k<<<32768, 256, 0, stream>>>(out, rs2, g2);
}

// Round 2
// 657.404 us; speedup vs baseline: 3.1951x; 3.1951x over previous
//
#include <hip/hip_runtime.h>
#include <hip/hip_bf16.h>
#include <math.h>

#define B_ 16
#define C_ 512
#define N_ 4096
#define NCOL (B_ * N_)  // 65536 columns (b, hw)

typedef short bf16x8 __attribute__((ext_vector_type(8)));
typedef float f32x4 __attribute__((ext_vector_type(4)));

__device__ __forceinline__ ushort f2bf(float f) {
    unsigned u = __float_as_uint(f);
    unsigned r = (u + 0x7FFFu + ((u >> 16) & 1u)) >> 16;
    return (ushort)r;
}
__device__ __forceinline__ float bf2f(ushort u) {
    return __uint_as_float((unsigned)u << 16);
}
__device__ __forceinline__ void gload_lds16(const void* g, void* l) {
    __builtin_amdgcn_global_load_lds(
        (const __attribute__((address_space(1))) unsigned int*)g,
        (__attribute__((address_space(3))) unsigned int*)l, 16, 0, 0);
}

// ---------------------------------------------------------------------------
// per-column L2 norm over 512 channels -> rs = sqrt(512)/max(||x||,eps)
// ---------------------------------------------------------------------------
__global__ __launch_bounds__(256) void colnorm_k(const float* __restrict__ X,
                                                 float* __restrict__ rs)
{
    int col = blockIdx.x * 256 + threadIdx.x;   // 0..65535
    int b = col >> 12, n = col & 4095;
    const float* p = X + ((size_t)b * C_) * N_ + n;
    float s = 0.f;
    #pragma unroll 8
    for (int c = 0; c < C_; ++c) {
        float v = p[(size_t)c * N_];
        s += v * v;
    }
    rs[col] = 22.627416998f / fmaxf(sqrtf(s), 1e-12f);
}

// ---------------------------------------------------------------------------
// weight prep: Wb[i] = bf16(W[i] * g[c])  (g optional, c = flat%512)
// ---------------------------------------------------------------------------
__global__ __launch_bounds__(256) void wprep_k(const float* __restrict__ W,
                                               const float* __restrict__ g,
                                               ushort* __restrict__ Wb, int nvec)
{
    int i = blockIdx.x * 256 + threadIdx.x;
    if (i >= nvec) return;
    float4 wv = reinterpret_cast<const float4*>(W)[i];
    if (g) {
        const float4 gv = *reinterpret_cast<const float4*>(g + ((i * 4) & 511));
        wv.x *= gv.x; wv.y *= gv.y; wv.z *= gv.z; wv.w *= gv.w;
    }
    ushort4 u;
    u.x = f2bf(wv.x); u.y = f2bf(wv.y); u.z = f2bf(wv.z); u.w = f2bf(wv.w);
    reinterpret_cast<ushort4*>(Wb)[i] = u;
}

// ---------------------------------------------------------------------------
// transpose+convert: Xt[b][n][c] = bf16(x[b][c][n] * rs[b][n])
// 64x64 tiles via LDS.
// ---------------------------------------------------------------------------
__global__ __launch_bounds__(256) void transpose_k(const float* __restrict__ X,
                                                   const float* __restrict__ rs,
                                                   ushort* __restrict__ Xt)
{
    __shared__ float t[64][65];
    const int b = blockIdx.z, n0 = blockIdx.x * 64, c0 = blockIdx.y * 64;
    const int tid = threadIdx.x;
    const int tx = tid & 63, ty = tid >> 6;
    const float* xp = X + ((size_t)b * C_ + c0) * N_ + n0;
    #pragma unroll
    for (int i = 0; i < 16; ++i)
        t[ty + 4 * i][tx] = xp[(size_t)(ty + 4 * i) * N_ + tx];
    __syncthreads();
    #pragma unroll
    for (int i = 0; i < 4; ++i) {
        int nl = (tid >> 4) + i * 16;
        int cl = (tid & 15) * 4;
        float s = rs[(size_t)b * N_ + n0 + nl];
        ushort4 u;
        u.x = f2bf(t[cl + 0][nl] * s);
        u.y = f2bf(t[cl + 1][nl] * s);
        u.z = f2bf(t[cl + 2][nl] * s);
        u.w = f2bf(t[cl + 3][nl] * s);
        *reinterpret_cast<ushort4*>(Xt + ((size_t)b * N_ + n0 + nl) * 512 + c0 + cl) = u;
    }
}

// ---------------------------------------------------------------------------
// MFMA GEMM: C[b][o][n] = sum_c A[o][c] * Bt[b][n][c]   (A,Bt bf16, K=512)
// 128x128 tile, 4 waves 2x2, 64x64/wave, BK=64, global_load_lds staging with
// XOR chunk swizzle (chunk ^= row&7) pre-applied on the global source address.
// MODE 0: route o>>9 -> q(f32) / k(f32) / v(bf16).  MODE 1: +bias -> out f32.
// ---------------------------------------------------------------------------
template <int MODE>
__global__ __launch_bounds__(256)
void mfma_gemm(const ushort* __restrict__ A, const ushort* __restrict__ Bt,
               float* __restrict__ qd, float* __restrict__ kd,
               ushort* __restrict__ vd,
               const float* __restrict__ bias, float* __restrict__ outp)
{
    __shared__ __align__(16) ushort As[128 * 64];
    __shared__ __align__(16) ushort Bs[128 * 64];
    const int b  = blockIdx.z;
    const int n0 = blockIdx.x * 128;
    const int m0 = blockIdx.y * 128;
    const int tid = threadIdx.x;
    const int w = tid >> 6, l = tid & 63;
    const int wm = w >> 1, wn = w & 1;
    const int lq = l >> 4, lr = l & 15;
    const ushort* Bb = Bt + (size_t)b * N_ * 512;

    f32x4 acc[4][4];
    #pragma unroll
    for (int i = 0; i < 4; ++i)
        #pragma unroll
        for (int j = 0; j < 4; ++j)
            #pragma unroll
            for (int r = 0; r < 4; ++r) acc[i][j][r] = 0.f;

    for (int k0 = 0; k0 < 512; k0 += 64) {
        #pragma unroll
        for (int i = 0; i < 4; ++i) {
            int r  = (w * 4 + i) * 8 + (l >> 3);       // 0..127
            int ch = (l & 7) ^ (r & 7);                // swizzled source chunk
            gload_lds16((const char*)A  + (size_t)(m0 + r) * 1024 + k0 * 2 + ch * 16,
                        (char*)As + (size_t)(w * 4 + i) * 1024);
            gload_lds16((const char*)Bb + (size_t)(n0 + r) * 1024 + k0 * 2 + ch * 16,
                        (char*)Bs + (size_t)(w * 4 + i) * 1024);
        }
        __syncthreads();
        #pragma unroll
        for (int kk = 0; kk < 2; ++kk) {
            bf16x8 af[4], bfr[4];
            #pragma unroll
            for (int mf = 0; mf < 4; ++mf) {
                int ra = wm * 64 + mf * 16 + lr;
                int ch = (kk * 4 + lq) ^ (ra & 7);
                af[mf] = *(const bf16x8*)((const char*)As + ra * 128 + ch * 16);
            }
            #pragma unroll
            for (int nf = 0; nf < 4; ++nf) {
                int rb = wn * 64 + nf * 16 + lr;
                int ch = (kk * 4 + lq) ^ (rb & 7);
                bfr[nf] = *(const bf16x8*)((const char*)Bs + rb * 128 + ch * 16);
            }
            #pragma unroll
            for (int mf = 0; mf < 4; ++mf)
                #pragma unroll
                for (int nf = 0; nf < 4; ++nf)
                    acc[mf][nf] = __builtin_amdgcn_mfma_f32_16x16x32_bf16(
                        af[mf], bfr[nf], acc[mf][nf], 0, 0, 0);
        }
        __syncthreads();
    }

    const int ncol = n0 + wn * 64 + lr;
    if constexpr (MODE == 0) {
        const int part = m0 >> 9;                    // uniform per block
        const int mb = (m0 & 511) + wm * 64 + lq * 4;
        #pragma unroll
        for (int mf = 0; mf < 4; ++mf) {
            int o = mb + mf * 16;
            #pragma unroll
            for (int nf = 0; nf < 4; ++nf) {
                int n = ncol + nf * 16;
                if (part == 2) {
                    ushort* p = vd + ((size_t)b * 512 + o) * N_ + n;
                    #pragma unroll
                    for (int r = 0; r < 4; ++r) p[(size_t)r * N_] = f2bf(acc[mf][nf][r]);
                } else {
                    float* dst = (part == 0) ? qd : kd;
                    float* p = dst + ((size_t)b * 512 + o) * N_ + n;
                    #pragma unroll
                    for (int r = 0; r < 4; ++r) p[(size_t)r * N_] = acc[mf][nf][r];
                }
            }
        }
    } else {
        const int mb = m0 + wm * 64 + lq * 4;
        #pragma unroll
        for (int mf = 0; mf < 4; ++mf) {
            int o = mb + mf * 16;
            #pragma unroll
            for (int nf = 0; nf < 4; ++nf) {
                int n = ncol + nf * 16;
                float* p = outp + ((size_t)b * 512 + o) * N_ + n;
                #pragma unroll
                for (int r = 0; r < 4; ++r) p[(size_t)r * N_] = acc[mf][nf][r] + bias[o + r];
            }
        }
    }
}

// ---------------------------------------------------------------------------
// softmax over d (64, stride 4096) per (b,h,n), then *0.125
// ---------------------------------------------------------------------------
__global__ __launch_bounds__(256) void softmax_d_k(float* __restrict__ q)
{
    int idx = blockIdx.x * 256 + threadIdx.x;
    int n = idx & 4095, bh = idx >> 12;
    float* p = q + (size_t)bh * 64 * N_ + n;
    float vals[64];
    float m = -1e30f;
    #pragma unroll
    for (int d = 0; d < 64; ++d) { vals[d] = p[(size_t)d * N_]; m = fmaxf(m, vals[d]); }
    float s = 0.f;
    #pragma unroll
    for (int d = 0; d < 64; ++d) { vals[d] = expf(vals[d] - m); s += vals[d]; }
    float r = 0.125f / s;
    #pragma unroll
    for (int d = 0; d < 64; ++d) p[(size_t)d * N_] = vals[d] * r;
}

// ---------------------------------------------------------------------------
// softmax over n (4096 contiguous) per (b,h,d) row
// ---------------------------------------------------------------------------
__global__ __launch_bounds__(256) void softmax_n_k(float* __restrict__ kk)
{
    float* p = kk + (size_t)blockIdx.x * N_;
    const int tid = threadIdx.x;
    float v[16];
    float m = -1e30f;
    #pragma unroll
    for (int i = 0; i < 16; ++i) { v[i] = p[tid + i * 256]; m = fmaxf(m, v[i]); }
    #pragma unroll
    for (int o = 32; o >= 1; o >>= 1) m = fmaxf(m, __shfl_xor(m, o));
    __shared__ float red[4];
    const int wid = tid >> 6, lane = tid & 63;
    if (lane == 0) red[wid] = m;
    __syncthreads();
    m = fmaxf(fmaxf(red[0], red[1]), fmaxf(red[2], red[3]));
    float s = 0.f;
    #pragma unroll
    for (int i = 0; i < 16; ++i) { v[i] = expf(v[i] - m); s += v[i]; }
    #pragma unroll
    for (int o = 32; o >= 1; o >>= 1) s += __shfl_xor(s, o);
    __syncthreads();
    if (lane == 0) red[wid] = s;
    __syncthreads();
    s = red[0] + red[1] + red[2] + red[3];
    float r = 1.f / s;
    #pragma unroll
    for (int i = 0; i < 16; ++i) p[tid + i * 256] = v[i] * r;
}

// ---------------------------------------------------------------------------
// context partial: ctxp[bh*4+chunk][d][e] = sum_{n in chunk} k[bh][d][n]*v[bh][e][n]
// v is bf16. grid (128, 4).
// ---------------------------------------------------------------------------
__global__ __launch_bounds__(256) void ctx_k(const float* __restrict__ kk,
                                             const ushort* __restrict__ vv,
                                             float* __restrict__ ctxp)
{
    const int bh = blockIdx.x, chunk = blockIdx.y;
    const float* kp = kk + (size_t)bh * 64 * N_;
    const ushort* vp = vv + (size_t)bh * 64 * N_;
    __shared__ float ks[64][129];
    __shared__ float vs[64][129];
    const int tid = threadIdx.x;
    const int td = tid >> 4, te = tid & 15;
    float acc[4][4] = {};
    for (int n0 = chunk * 1024; n0 < chunk * 1024 + 1024; n0 += 128) {
        #pragma unroll
        for (int i = 0; i < 32; ++i) {
            int idx = i * 256 + tid;
            int d = idx >> 7, nn = idx & 127;
            ks[d][nn] = kp[(size_t)d * N_ + n0 + nn];
            vs[d][nn] = bf2f(vp[(size_t)d * N_ + n0 + nn]);
        }
        __syncthreads();
        for (int nn = 0; nn < 128; ++nn) {
            float a[4], bb[4];
            #pragma unroll
            for (int i = 0; i < 4; ++i) a[i]  = ks[td * 4 + i][nn];
            #pragma unroll
            for (int j = 0; j < 4; ++j) bb[j] = vs[te * 4 + j][nn];
            #pragma unroll
            for (int i = 0; i < 4; ++i)
                #pragma unroll
                for (int j = 0; j < 4; ++j)
                    acc[i][j] = fmaf(a[i], bb[j], acc[i][j]);
        }
        __syncthreads();
    }
    #pragma unroll
    for (int i = 0; i < 4; ++i)
        #pragma unroll
        for (int j = 0; j < 4; ++j)
            ctxp[((size_t)bh * 4 + chunk) * 4096 + (td * 4 + i) * 64 + te * 4 + j] = acc[i][j];
}

// ---------------------------------------------------------------------------
// attn: at2[b][n][h*64+e] = bf16( sum_d ctx[bh][d][e] * q[bh][d][n] )
// ctx summed over 4 partials. q read from d_out.
// ---------------------------------------------------------------------------
__global__ __launch_bounds__(256) void attn_k(const float* __restrict__ ctxp,
                                              const float* __restrict__ q,
                                              ushort* __restrict__ at2)
{
    const int bh = blockIdx.y;
    const int n0 = blockIdx.x * 256;
    __shared__ __align__(16) float ctx_s[64][64];
    __shared__ __align__(16) float q_s[64][256];
    const float* cp = ctxp + (size_t)bh * 4 * 4096;
    const float* qp = q + (size_t)bh * 64 * N_;
    const int tid = threadIdx.x;
    #pragma unroll
    for (int i = 0; i < 16; ++i) {
        int idx = i * 256 + tid;
        ctx_s[idx >> 6][idx & 63] = cp[idx] + cp[idx + 4096] + cp[idx + 8192] + cp[idx + 12288];
    }
    #pragma unroll 4
    for (int d = 0; d < 64; ++d)
        q_s[d][tid] = qp[(size_t)d * N_ + n0 + tid];
    __syncthreads();
    const int eg = tid >> 6;
    const int ng = tid & 63;
    float acc[16][4] = {};
    for (int d = 0; d < 64; ++d) {
        float qv[4];
        *(float4*)qv = *(float4*)&q_s[d][ng * 4];
        float cv[16];
        #pragma unroll
        for (int t = 0; t < 4; ++t)
            *(float4*)&cv[t * 4] = *(float4*)&ctx_s[d][eg * 16 + t * 4];
        #pragma unroll
        for (int e = 0; e < 16; ++e)
            #pragma unroll
            for (int j = 0; j < 4; ++j)
                acc[e][j] = fmaf(cv[e], qv[j], acc[e][j]);
    }
    const int b = bh >> 3, h = bh & 7;
    ushort* op = at2 + ((size_t)b * N_ + n0 + ng * 4) * 512 + h * 64 + eg * 16;
    #pragma unroll
    for (int j = 0; j < 4; ++j) {
        ushort4* pp = (ushort4*)(op + (size_t)j * 512);
        ushort4 u;
        u.x=f2bf(acc[0][j]);  u.y=f2bf(acc[1][j]);  u.z=f2bf(acc[2][j]);  u.w=f2bf(acc[3][j]);  pp[0]=u;
        u.x=f2bf(acc[4][j]);  u.y=f2bf(acc[5][j]);  u.z=f2bf(acc[6][j]);  u.w=f2bf(acc[7][j]);  pp[1]=u;
        u.x=f2bf(acc[8][j]);  u.y=f2bf(acc[9][j]);  u.z=f2bf(acc[10][j]); u.w=f2bf(acc[11][j]); pp[2]=u;
        u.x=f2bf(acc[12][j]); u.y=f2bf(acc[13][j]); u.z=f2bf(acc[14][j]); u.w=f2bf(acc[15][j]); pp[3]=u;
    }
}

// ---------------------------------------------------------------------------
// final rms-norm apply: out[b][o][n] *= rs2[b][n] * g2[o]
// ---------------------------------------------------------------------------
__global__ __launch_bounds__(256) void scale_k(float* __restrict__ out,
                                               const float* __restrict__ rs,
                                               const float* __restrict__ g2)
{
    size_t f = (size_t)blockIdx.x * 256 + threadIdx.x;
    size_t e = f * 4;
    int o = (int)((e >> 12) & 511);
    int b = (int)(e >> 21);
    int n = (int)(e & 4095);
    float4 v = reinterpret_cast<float4*>(out)[f];
    float4 s = *reinterpret_cast<const float4*>(&rs[(size_t)b * 4096 + n]);
    float g = g2[o];
    v.x *= s.x * g; v.y *= s.y * g; v.z *= s.z * g; v.w *= s.w * g;
    reinterpret_cast<float4*>(out)[f] = v;
}

// ---------------------------------------------------------------------------
extern "C" void kernel_launch(void* const* d_in, const int* in_sizes, int n_in,
                              void* d_out, int out_size, void* d_ws, size_t ws_size,
                              hipStream_t stream)
{
    const float* x    = (const float*)d_in[0];
    const float* g1   = (const float*)d_in[1];
    const float* Wqkv = (const float*)d_in[2];
    const float* Wout = (const float*)d_in[3];
    const float* bout = (const float*)d_in[4];
    const float* g2   = (const float*)d_in[5];
    float* out = (float*)d_out;

    // ws layout (258.5 MiB):
    //   [0,128Mi)    kbuf f32 (k)         -> later reused: at2 bf16 (first 64Mi)
    //   [128,192Mi)  vbuf bf16 (v)
    //   [192,256Mi)  Xt bf16              -> later reused: ctxp f32 (8Mi)
    //   [256Mi..)    Wqkvb(1.5Mi) Woutb(0.5Mi) rs1(256Ki) rs2(256Ki)
    char* wsb = (char*)d_ws;
    float*  kbuf  = (float*)wsb;
    ushort* vbuf  = (ushort*)(wsb + ((size_t)128 << 20));
    ushort* Xt    = (ushort*)(wsb + ((size_t)192 << 20));
    char*   tail  = wsb + ((size_t)256 << 20);
    ushort* Wqkvb = (ushort*)tail;
    ushort* Woutb = (ushort*)(tail + 1536 * 512 * 2);
    float*  rs1   = (float*)(tail + 1536 * 512 * 2 + 512 * 512 * 2);
    float*  rs2   = rs1 + NCOL;
    float*  ctxp  = (float*)Xt;       // 8 MiB, alias after GEMM1 consumed Xt
    ushort* at2   = (ushort*)kbuf;    // 64 MiB, alias after ctx_k consumed k

    // 1. column norms of x
    colnorm_k<<<NCOL / 256, 256, 0, stream>>>(x, rs1);
    // 2. weight prep (bf16; g1 folded into Wqkv)
    wprep_k<<<768, 256, 0, stream>>>(Wqkv, g1, Wqkvb, 1536 * 512 / 4);
    wprep_k<<<256, 256, 0, stream>>>(Wout, nullptr, Woutb, 512 * 512 / 4);
    // 3. Xt[b][n][c] = bf16(x * rs1)  (rms-norm folded)
    transpose_k<<<dim3(64, 8, 16), 256, 0, stream>>>(x, rs1, Xt);
    // 4. QKV GEMM (MFMA): q -> d_out f32, k -> kbuf f32, v -> vbuf bf16
    mfma_gemm<0><<<dim3(32, 12, B_), 256, 0, stream>>>(Wqkvb, Xt, out, kbuf, vbuf,
                                                       nullptr, nullptr);
    // 5. softmax over d on q
    softmax_d_k<<<(B_ * 8 * N_) / 256, 256, 0, stream>>>(out);
    // 6. softmax over n on k
    softmax_n_k<<<B_ * 8 * 64, 256, 0, stream>>>(kbuf);
    // 7. context partials (4 n-chunks)
    ctx_k<<<dim3(B_ * 8, 4), 256, 0, stream>>>(kbuf, vbuf, ctxp);
    // 8. attn -> at2 bf16 [b][n][hid] (k dead, q consumed here)
    attn_k<<<dim3(N_ / 256, B_ * 8), 256, 0, stream>>>(ctxp, out, at2);
    // 9. output GEMM (MFMA) + bias -> d_out f32
    mfma_gemm<1><<<dim3(32, 4, B_), 256, 0, stream>>>(Woutb, at2, nullptr, nullptr,
                                                      nullptr, bout, out);
    // 10-11. final rms-norm
    colnorm_k<<<NCOL / 256, 256, 0, stream>>>(out, rs2);
    scale_k<<<32768, 256, 0, stream>>>(out, rs2, g2);
}

// Round 3
// 536.633 us; speedup vs baseline: 3.9142x; 1.2251x over previous
//
#include <hip/hip_runtime.h>
#include <hip/hip_bf16.h>
#include <math.h>

#define B_ 16
#define C_ 512
#define N_ 4096
#define NCOL (B_ * N_)  // 65536 columns (b, hw)

typedef short bf16x8 __attribute__((ext_vector_type(8)));
typedef ushort ushort8_t __attribute__((ext_vector_type(8)));
typedef float f32x4 __attribute__((ext_vector_type(4)));

__device__ __forceinline__ ushort f2bf(float f) {
    unsigned u = __float_as_uint(f);
    unsigned r = (u + 0x7FFFu + ((u >> 16) & 1u)) >> 16;
    return (ushort)r;
}
__device__ __forceinline__ float bf2f(ushort u) {
    return __uint_as_float((unsigned)u << 16);
}
__device__ __forceinline__ void gload_lds16(const void* g, void* l) {
    __builtin_amdgcn_global_load_lds(
        (const __attribute__((address_space(1))) unsigned int*)g,
        (__attribute__((address_space(3))) unsigned int*)l, 16, 0, 0);
}

// ---------------------------------------------------------------------------
// per-column L2 norm over 512 channels -> rs = sqrt(512)/max(||x||,eps)
// ---------------------------------------------------------------------------
__global__ __launch_bounds__(256) void colnorm_k(const float* __restrict__ X,
                                                 float* __restrict__ rs)
{
    int col = blockIdx.x * 256 + threadIdx.x;   // 0..65535
    int b = col >> 12, n = col & 4095;
    const float* p = X + ((size_t)b * C_) * N_ + n;
    float s = 0.f;
    #pragma unroll 8
    for (int c = 0; c < C_; ++c) {
        float v = p[(size_t)c * N_];
        s += v * v;
    }
    rs[col] = 22.627416998f / fmaxf(sqrtf(s), 1e-12f);
}

// ---------------------------------------------------------------------------
// weight prep: Wb[i] = bf16(W[i] * g[c])  (g optional, c = flat%512)
// ---------------------------------------------------------------------------
__global__ __launch_bounds__(256) void wprep_k(const float* __restrict__ W,
                                               const float* __restrict__ g,
                                               ushort* __restrict__ Wb, int nvec)
{
    int i = blockIdx.x * 256 + threadIdx.x;
    if (i >= nvec) return;
    float4 wv = reinterpret_cast<const float4*>(W)[i];
    if (g) {
        const float4 gv = *reinterpret_cast<const float4*>(g + ((i * 4) & 511));
        wv.x *= gv.x; wv.y *= gv.y; wv.z *= gv.z; wv.w *= gv.w;
    }
    ushort4 u;
    u.x = f2bf(wv.x); u.y = f2bf(wv.y); u.z = f2bf(wv.z); u.w = f2bf(wv.w);
    reinterpret_cast<ushort4*>(Wb)[i] = u;
}

// ---------------------------------------------------------------------------
// transpose+convert: Xt[b][n][c] = bf16(x[b][c][n])   (norm applied in GEMM1)
// ---------------------------------------------------------------------------
__global__ __launch_bounds__(256) void transpose_k(const float* __restrict__ X,
                                                   ushort* __restrict__ Xt)
{
    __shared__ float t[64][65];
    const int b = blockIdx.z, n0 = blockIdx.x * 64, c0 = blockIdx.y * 64;
    const int tid = threadIdx.x;
    const int tx = tid & 63, ty = tid >> 6;
    const float* xp = X + ((size_t)b * C_ + c0) * N_ + n0;
    #pragma unroll
    for (int i = 0; i < 16; ++i)
        t[ty + 4 * i][tx] = xp[(size_t)(ty + 4 * i) * N_ + tx];
    __syncthreads();
    #pragma unroll
    for (int i = 0; i < 4; ++i) {
        int nl = (tid >> 4) + i * 16;
        int cl = (tid & 15) * 4;
        ushort4 u;
        u.x = f2bf(t[cl + 0][nl]);
        u.y = f2bf(t[cl + 1][nl]);
        u.z = f2bf(t[cl + 2][nl]);
        u.w = f2bf(t[cl + 3][nl]);
        *reinterpret_cast<ushort4*>(Xt + ((size_t)b * N_ + n0 + nl) * 512 + c0 + cl) = u;
    }
}

// ---------------------------------------------------------------------------
// MFMA GEMM: acc[o][n] = sum_c A[o][c] * Bt[b][n][c]   (A,Bt bf16, K=512)
// 128x128 tile, 4 waves 2x2, BK=64, global_load_lds + XOR chunk swizzle.
// MODE 0 epilogue: acc *= rs1[b][n];
//   part 0 (q): softmax over d (in-wave reduce) * 0.125 -> q bf16
//   part 1/2 (k/v): -> bf16 raw
// MODE 1 epilogue: out = acc + bias (f32) + per-column sumsq partial -> colsq
// ---------------------------------------------------------------------------
template <int MODE>
__global__ __launch_bounds__(256)
void mfma_gemm(const ushort* __restrict__ A, const ushort* __restrict__ Bt,
               const float* __restrict__ rs1,
               ushort* __restrict__ qd, ushort* __restrict__ kd,
               ushort* __restrict__ vd,
               const float* __restrict__ bias, float* __restrict__ outp,
               float* __restrict__ colsq)
{
    __shared__ __align__(16) ushort As[128 * 64];
    __shared__ __align__(16) ushort Bs[128 * 64];
    const int b  = blockIdx.z;
    const int n0 = blockIdx.x * 128;
    const int m0 = blockIdx.y * 128;
    const int tid = threadIdx.x;
    const int w = tid >> 6, l = tid & 63;
    const int wm = w >> 1, wn = w & 1;
    const int lq = l >> 4, lr = l & 15;
    const ushort* Bb = Bt + (size_t)b * N_ * 512;

    f32x4 acc[4][4];
    #pragma unroll
    for (int i = 0; i < 4; ++i)
        #pragma unroll
        for (int j = 0; j < 4; ++j)
            #pragma unroll
            for (int r = 0; r < 4; ++r) acc[i][j][r] = 0.f;

    for (int k0 = 0; k0 < 512; k0 += 64) {
        #pragma unroll
        for (int i = 0; i < 4; ++i) {
            int r  = (w * 4 + i) * 8 + (l >> 3);       // 0..127
            int ch = (l & 7) ^ (r & 7);                // swizzled source chunk
            gload_lds16((const char*)A  + (size_t)(m0 + r) * 1024 + k0 * 2 + ch * 16,
                        (char*)As + (size_t)(w * 4 + i) * 1024);
            gload_lds16((const char*)Bb + (size_t)(n0 + r) * 1024 + k0 * 2 + ch * 16,
                        (char*)Bs + (size_t)(w * 4 + i) * 1024);
        }
        __syncthreads();
        #pragma unroll
        for (int kk = 0; kk < 2; ++kk) {
            bf16x8 af[4], bfr[4];
            #pragma unroll
            for (int mf = 0; mf < 4; ++mf) {
                int ra = wm * 64 + mf * 16 + lr;
                int ch = (kk * 4 + lq) ^ (ra & 7);
                af[mf] = *(const bf16x8*)((const char*)As + ra * 128 + ch * 16);
            }
            #pragma unroll
            for (int nf = 0; nf < 4; ++nf) {
                int rb = wn * 64 + nf * 16 + lr;
                int ch = (kk * 4 + lq) ^ (rb & 7);
                bfr[nf] = *(const bf16x8*)((const char*)Bs + rb * 128 + ch * 16);
            }
            #pragma unroll
            for (int mf = 0; mf < 4; ++mf)
                #pragma unroll
                for (int nf = 0; nf < 4; ++nf)
                    acc[mf][nf] = __builtin_amdgcn_mfma_f32_16x16x32_bf16(
                        af[mf], bfr[nf], acc[mf][nf], 0, 0, 0);
        }
        __syncthreads();
    }

    const int ncol = n0 + wn * 64 + lr;
    if constexpr (MODE == 0) {
        const int part = m0 >> 9;                      // block-uniform
        const int mrow = (m0 & 511) + wm * 64;         // wave-uniform row base
        if (part == 0) {
            // q: *rs1, softmax over d (rows of this wave), *0.125, bf16
            const size_t bh = (size_t)b * 8 + (mrow >> 6);
            #pragma unroll
            for (int nf = 0; nf < 4; ++nf) {
                const int n = ncol + nf * 16;
                const float sc = rs1[(size_t)b * N_ + n];
                float v[4][4];
                float mx = -1e30f;
                #pragma unroll
                for (int mf = 0; mf < 4; ++mf)
                    #pragma unroll
                    for (int r = 0; r < 4; ++r) {
                        v[mf][r] = acc[mf][nf][r] * sc;
                        mx = fmaxf(mx, v[mf][r]);
                    }
                mx = fmaxf(mx, __shfl_xor(mx, 16));
                mx = fmaxf(mx, __shfl_xor(mx, 32));
                float s = 0.f;
                #pragma unroll
                for (int mf = 0; mf < 4; ++mf)
                    #pragma unroll
                    for (int r = 0; r < 4; ++r) {
                        v[mf][r] = __expf(v[mf][r] - mx);
                        s += v[mf][r];
                    }
                s += __shfl_xor(s, 16);
                s += __shfl_xor(s, 32);
                const float r8 = 0.125f / s;
                #pragma unroll
                for (int mf = 0; mf < 4; ++mf)
                    #pragma unroll
                    for (int r = 0; r < 4; ++r)
                        qd[(bh * 64 + mf * 16 + lq * 4 + r) * N_ + n] =
                            f2bf(v[mf][r] * r8);
            }
        } else {
            ushort* dst = (part == 1) ? kd : vd;
            const int mb = mrow + lq * 4;
            #pragma unroll
            for (int nf = 0; nf < 4; ++nf) {
                const int n = ncol + nf * 16;
                const float sc = rs1[(size_t)b * N_ + n];
                #pragma unroll
                for (int mf = 0; mf < 4; ++mf) {
                    const int o = mb + mf * 16;
                    #pragma unroll
                    for (int r = 0; r < 4; ++r)
                        dst[((size_t)b * 512 + o + r) * N_ + n] =
                            f2bf(acc[mf][nf][r] * sc);
                }
            }
        }
    } else {
        const int mb = m0 + wm * 64 + lq * 4;
        float csq[4] = {0.f, 0.f, 0.f, 0.f};
        #pragma unroll
        for (int mf = 0; mf < 4; ++mf) {
            const int o = mb + mf * 16;
            #pragma unroll
            for (int nf = 0; nf < 4; ++nf) {
                const int n = ncol + nf * 16;
                float* p = outp + ((size_t)b * 512 + o) * N_ + n;
                #pragma unroll
                for (int r = 0; r < 4; ++r) {
                    float wv = acc[mf][nf][r] + bias[o + r];
                    p[(size_t)r * N_] = wv;
                    csq[nf] += wv * wv;
                }
            }
        }
        // reduce sumsq over lq lanes, then over wm via LDS
        #pragma unroll
        for (int nf = 0; nf < 4; ++nf) {
            csq[nf] += __shfl_xor(csq[nf], 16);
            csq[nf] += __shfl_xor(csq[nf], 32);
        }
        float* red = (float*)As;   // LDS free after last barrier
        if (lq == 0) {
            #pragma unroll
            for (int nf = 0; nf < 4; ++nf)
                red[wm * 128 + wn * 64 + nf * 16 + lr] = csq[nf];
        }
        __syncthreads();
        if (tid < 128)
            colsq[(size_t)blockIdx.y * NCOL + (size_t)b * N_ + n0 + tid] =
                red[tid] + red[128 + tid];
    }
}

// ---------------------------------------------------------------------------
// row stats for k-softmax: per row (bh*64+d) of 4096 bf16 scores ->
// rowm = max, rowr = 1/sum(exp(v-max)).  One wave per row.
// ---------------------------------------------------------------------------
__global__ __launch_bounds__(256) void rowstat_k(const ushort* __restrict__ kk,
                                                 float* __restrict__ rowm,
                                                 float* __restrict__ rowr)
{
    const int row = blockIdx.x * 4 + (threadIdx.x >> 6);
    const int lane = threadIdx.x & 63;
    const ushort* p = kk + (size_t)row * N_;
    float vals[64];
    #pragma unroll
    for (int j = 0; j < 8; ++j) {
        ushort8_t u = *reinterpret_cast<const ushort8_t*>(p + lane * 8 + j * 512);
        #pragma unroll
        for (int t = 0; t < 8; ++t) vals[j * 8 + t] = bf2f(u[t]);
    }
    float mx = -1e30f;
    #pragma unroll
    for (int i = 0; i < 64; ++i) mx = fmaxf(mx, vals[i]);
    #pragma unroll
    for (int o = 32; o >= 1; o >>= 1) mx = fmaxf(mx, __shfl_xor(mx, o));
    float s = 0.f;
    #pragma unroll
    for (int i = 0; i < 64; ++i) s += __expf(vals[i] - mx);
    #pragma unroll
    for (int o = 32; o >= 1; o >>= 1) s += __shfl_xor(s, o);
    if (lane == 0) { rowm[row] = mx; rowr[row] = 1.f / s; }
}

// ---------------------------------------------------------------------------
// context partial: ctxp[bh*4+chunk][d][e] =
//   rowr[d] * sum_{n in chunk} exp(k[bh][d][n]-rowm[d]) * v[bh][e][n]
// k,v bf16. grid (128, 4).
// ---------------------------------------------------------------------------
__global__ __launch_bounds__(256) void ctx_k(const ushort* __restrict__ kk,
                                             const ushort* __restrict__ vv,
                                             const float* __restrict__ rowm,
                                             const float* __restrict__ rowr,
                                             float* __restrict__ ctxp)
{
    const int bh = blockIdx.x, chunk = blockIdx.y;
    const ushort* kp = kk + (size_t)bh * 64 * N_;
    const ushort* vp = vv + (size_t)bh * 64 * N_;
    __shared__ float ks[64][129];
    __shared__ float vs[64][129];
    __shared__ float rm[64];
    const int tid = threadIdx.x;
    if (tid < 64) rm[tid] = rowm[(size_t)bh * 64 + tid];
    __syncthreads();
    const int td = tid >> 4, te = tid & 15;
    float acc[4][4] = {};
    for (int n0 = chunk * 1024; n0 < chunk * 1024 + 1024; n0 += 128) {
        #pragma unroll
        for (int i = 0; i < 32; ++i) {
            int idx = i * 256 + tid;
            int d = idx >> 7, nn = idx & 127;
            ks[d][nn] = __expf(bf2f(kp[(size_t)d * N_ + n0 + nn]) - rm[d]);
            vs[d][nn] = bf2f(vp[(size_t)d * N_ + n0 + nn]);
        }
        __syncthreads();
        for (int nn = 0; nn < 128; ++nn) {
            float a[4], bb[4];
            #pragma unroll
            for (int i = 0; i < 4; ++i) a[i]  = ks[td * 4 + i][nn];
            #pragma unroll
            for (int j = 0; j < 4; ++j) bb[j] = vs[te * 4 + j][nn];
            #pragma unroll
            for (int i = 0; i < 4; ++i)
                #pragma unroll
                for (int j = 0; j < 4; ++j)
                    acc[i][j] = fmaf(a[i], bb[j], acc[i][j]);
        }
        __syncthreads();
    }
    float rrv[4];
    #pragma unroll
    for (int i = 0; i < 4; ++i) rrv[i] = rowr[(size_t)bh * 64 + td * 4 + i];
    #pragma unroll
    for (int i = 0; i < 4; ++i)
        #pragma unroll
        for (int j = 0; j < 4; ++j)
            ctxp[((size_t)bh * 4 + chunk) * 4096 + (td * 4 + i) * 64 + te * 4 + j] =
                acc[i][j] * rrv[i];
}

// ---------------------------------------------------------------------------
// attn: at2[b][n][h*64+e] = bf16( sum_d ctx[bh][d][e] * q[bh][d][n] )
// ctx summed over 4 partials. q bf16.
// ---------------------------------------------------------------------------
__global__ __launch_bounds__(256) void attn_k(const float* __restrict__ ctxp,
                                              const ushort* __restrict__ q,
                                              ushort* __restrict__ at2)
{
    const int bh = blockIdx.y;
    const int n0 = blockIdx.x * 256;
    __shared__ __align__(16) float ctx_s[64][64];
    __shared__ __align__(16) float q_s[64][256];
    const float* cp = ctxp + (size_t)bh * 4 * 4096;
    const ushort* qp = q + (size_t)bh * 64 * N_;
    const int tid = threadIdx.x;
    #pragma unroll
    for (int i = 0; i < 16; ++i) {
        int idx = i * 256 + tid;
        ctx_s[idx >> 6][idx & 63] = cp[idx] + cp[idx + 4096] + cp[idx + 8192] + cp[idx + 12288];
    }
    #pragma unroll 4
    for (int d = 0; d < 64; ++d)
        q_s[d][tid] = bf2f(qp[(size_t)d * N_ + n0 + tid]);
    __syncthreads();
    const int eg = tid >> 6;
    const int ng = tid & 63;
    float acc[16][4] = {};
    for (int d = 0; d < 64; ++d) {
        float qv[4];
        *(float4*)qv = *(float4*)&q_s[d][ng * 4];
        float cv[16];
        #pragma unroll
        for (int t = 0; t < 4; ++t)
            *(float4*)&cv[t * 4] = *(float4*)&ctx_s[d][eg * 16 + t * 4];
        #pragma unroll
        for (int e = 0; e < 16; ++e)
            #pragma unroll
            for (int j = 0; j < 4; ++j)
                acc[e][j] = fmaf(cv[e], qv[j], acc[e][j]);
    }
    const int b = bh >> 3, h = bh & 7;
    ushort* op = at2 + ((size_t)b * N_ + n0 + ng * 4) * 512 + h * 64 + eg * 16;
    #pragma unroll
    for (int j = 0; j < 4; ++j) {
        ushort4* pp = (ushort4*)(op + (size_t)j * 512);
        ushort4 u;
        u.x=f2bf(acc[0][j]);  u.y=f2bf(acc[1][j]);  u.z=f2bf(acc[2][j]);  u.w=f2bf(acc[3][j]);  pp[0]=u;
        u.x=f2bf(acc[4][j]);  u.y=f2bf(acc[5][j]);  u.z=f2bf(acc[6][j]);  u.w=f2bf(acc[7][j]);  pp[1]=u;
        u.x=f2bf(acc[8][j]);  u.y=f2bf(acc[9][j]);  u.z=f2bf(acc[10][j]); u.w=f2bf(acc[11][j]); pp[2]=u;
        u.x=f2bf(acc[12][j]); u.y=f2bf(acc[13][j]); u.z=f2bf(acc[14][j]); u.w=f2bf(acc[15][j]); pp[3]=u;
    }
}

// ---------------------------------------------------------------------------
// final rms-norm apply: out[b][o][n] *= g2[o] * sqrt512/max(sqrt(sum colsq),eps)
// ---------------------------------------------------------------------------
__global__ __launch_bounds__(256) void scale_k(float* __restrict__ out,
                                               const float* __restrict__ colsq,
                                               const float* __restrict__ g2)
{
    size_t f = (size_t)blockIdx.x * 256 + threadIdx.x;
    size_t e = f * 4;
    int o = (int)((e >> 12) & 511);
    int b = (int)(e >> 21);
    int n = (int)(e & 4095);
    size_t cb = (size_t)b * N_ + n;
    float4 s0 = *reinterpret_cast<const float4*>(&colsq[cb]);
    float4 s1 = *reinterpret_cast<const float4*>(&colsq[(size_t)NCOL + cb]);
    float4 s2 = *reinterpret_cast<const float4*>(&colsq[(size_t)2 * NCOL + cb]);
    float4 s3 = *reinterpret_cast<const float4*>(&colsq[(size_t)3 * NCOL + cb]);
    float g = g2[o];
    float4 v = reinterpret_cast<float4*>(out)[f];
    v.x *= g * 22.627416998f / fmaxf(sqrtf(s0.x + s1.x + s2.x + s3.x), 1e-12f);
    v.y *= g * 22.627416998f / fmaxf(sqrtf(s0.y + s1.y + s2.y + s3.y), 1e-12f);
    v.z *= g * 22.627416998f / fmaxf(sqrtf(s0.z + s1.z + s2.z + s3.z), 1e-12f);
    v.w *= g * 22.627416998f / fmaxf(sqrtf(s0.w + s1.w + s2.w + s3.w), 1e-12f);
    reinterpret_cast<float4*>(out)[f] = v;
}

// ---------------------------------------------------------------------------
extern "C" void kernel_launch(void* const* d_in, const int* in_sizes, int n_in,
                              void* d_out, int out_size, void* d_ws, size_t ws_size,
                              hipStream_t stream)
{
    const float* x    = (const float*)d_in[0];
    const float* g1   = (const float*)d_in[1];
    const float* Wqkv = (const float*)d_in[2];
    const float* Wout = (const float*)d_in[3];
    const float* bout = (const float*)d_in[4];
    const float* g2   = (const float*)d_in[5];
    float* out = (float*)d_out;

    // ws layout (<= 258.25 MiB):
    //   [0,64Mi)     qbuf bf16
    //   [64,128Mi)   kbuf bf16           -> at2 bf16 after ctx_k
    //   [128,192Mi)  vbuf bf16
    //   [192,256Mi)  Xt bf16             -> after GEMM1: ctxp f32 (8Mi) @192,
    //                                       rowm/rowr @200Mi, colsq4 @201Mi
    //   [256Mi..)    Wqkvb(1.5Mi) Woutb(0.5Mi) rs1(256Ki)
    char* wsb = (char*)d_ws;
    ushort* qbuf  = (ushort*)wsb;
    ushort* kbuf  = (ushort*)(wsb + ((size_t)64 << 20));
    ushort* vbuf  = (ushort*)(wsb + ((size_t)128 << 20));
    ushort* Xt    = (ushort*)(wsb + ((size_t)192 << 20));
    float*  ctxp  = (float*)Xt;
    float*  rowm  = (float*)(wsb + ((size_t)200 << 20));
    float*  rowr  = rowm + 8192;
    float*  colsq = (float*)(wsb + ((size_t)201 << 20));
    char*   tail  = wsb + ((size_t)256 << 20);
    ushort* Wqkvb = (ushort*)tail;
    ushort* Woutb = (ushort*)(tail + (size_t)1536 * 512 * 2);
    float*  rs1   = (float*)(tail + (size_t)1536 * 512 * 2 + (size_t)512 * 512 * 2);
    ushort* at2   = kbuf;   // alias: k dead after ctx_k

    // 1. column norms of x (applied in GEMM1 epilogue)
    colnorm_k<<<NCOL / 256, 256, 0, stream>>>(x, rs1);
    // 2. weight prep (bf16; g1 folded into Wqkv)
    wprep_k<<<768, 256, 0, stream>>>(Wqkv, g1, Wqkvb, 1536 * 512 / 4);
    wprep_k<<<256, 256, 0, stream>>>(Wout, nullptr, Woutb, 512 * 512 / 4);
    // 3. Xt[b][n][c] = bf16(x^T)
    transpose_k<<<dim3(64, 8, 16), 256, 0, stream>>>(x, Xt);
    // 4. QKV GEMM: q(softmaxed, bf16), k(raw bf16), v(bf16)
    mfma_gemm<0><<<dim3(32, 12, B_), 256, 0, stream>>>(Wqkvb, Xt, rs1,
                                                       qbuf, kbuf, vbuf,
                                                       nullptr, nullptr, nullptr);
    // 5. k row stats (max, 1/sum-exp)
    rowstat_k<<<2048, 256, 0, stream>>>(kbuf, rowm, rowr);
    // 6. context partials (softmax applied on the fly)
    ctx_k<<<dim3(B_ * 8, 4), 256, 0, stream>>>(kbuf, vbuf, rowm, rowr, ctxp);
    // 7. attn -> at2 bf16 [b][n][hid]
    attn_k<<<dim3(N_ / 256, B_ * 8), 256, 0, stream>>>(ctxp, qbuf, at2);
    // 8. output GEMM + bias -> d_out f32, + column sumsq partials
    mfma_gemm<1><<<dim3(32, 4, B_), 256, 0, stream>>>(Woutb, at2, nullptr,
                                                      nullptr, nullptr, nullptr,
                                                      bout, out, colsq);
    // 9. final rms-norm apply
    scale_k<<<32768, 256, 0, stream>>>(out, colsq, g2);
}

// Round 4
// 455.753 us; speedup vs baseline: 4.6088x; 1.1775x over previous
//
#include <hip/hip_runtime.h>
#include <hip/hip_bf16.h>
#include <math.h>

#define B_ 16
#define C_ 512
#define N_ 4096
#define NCOL (B_ * N_)  // 65536 columns (b, hw)

typedef short bf16x8 __attribute__((ext_vector_type(8)));
typedef ushort ushort8_t __attribute__((ext_vector_type(8)));
typedef float f32x4 __attribute__((ext_vector_type(4)));

__device__ __forceinline__ ushort f2bf(float f) {
    unsigned u = __float_as_uint(f);
    unsigned r = (u + 0x7FFFu + ((u >> 16) & 1u)) >> 16;
    return (ushort)r;
}
__device__ __forceinline__ float bf2f(ushort u) {
    return __uint_as_float((unsigned)u << 16);
}
__device__ __forceinline__ void gload_lds16(const void* g, void* l) {
    __builtin_amdgcn_global_load_lds(
        (const __attribute__((address_space(1))) unsigned int*)g,
        (__attribute__((address_space(3))) unsigned int*)l, 16, 0, 0);
}

// ---------------------------------------------------------------------------
// weight prep: Wb[i] = bf16(W[i] * g[c])  (g optional, c = flat%512)
// ---------------------------------------------------------------------------
__global__ __launch_bounds__(256) void wprep_k(const float* __restrict__ W,
                                               const float* __restrict__ g,
                                               ushort* __restrict__ Wb, int nvec)
{
    int i = blockIdx.x * 256 + threadIdx.x;
    if (i >= nvec) return;
    float4 wv = reinterpret_cast<const float4*>(W)[i];
    if (g) {
        const float4 gv = *reinterpret_cast<const float4*>(g + ((i * 4) & 511));
        wv.x *= gv.x; wv.y *= gv.y; wv.z *= gv.z; wv.w *= gv.w;
    }
    ushort4 u;
    u.x = f2bf(wv.x); u.y = f2bf(wv.y); u.z = f2bf(wv.z); u.w = f2bf(wv.w);
    reinterpret_cast<ushort4*>(Wb)[i] = u;
}

// ---------------------------------------------------------------------------
// transpose+convert+colnorm-partial:
//   Xt[b][n][c] = bf16(x[b][c][n]);  csq1[ctile][b*4096+n] += sum_c x^2
// ---------------------------------------------------------------------------
__global__ __launch_bounds__(256) void transpose_k(const float* __restrict__ X,
                                                   ushort* __restrict__ Xt,
                                                   float* __restrict__ csq1)
{
    __shared__ float t[64][65];
    __shared__ float sq[4][64];
    const int b = blockIdx.z, n0 = blockIdx.x * 64, c0 = blockIdx.y * 64;
    const int tid = threadIdx.x;
    const int tx = tid & 63, ty = tid >> 6;
    const float* xp = X + ((size_t)b * C_ + c0) * N_ + n0;
    float local = 0.f;
    #pragma unroll
    for (int i = 0; i < 16; ++i) {
        float v = xp[(size_t)(ty + 4 * i) * N_ + tx];
        t[ty + 4 * i][tx] = v;
        local += v * v;
    }
    sq[ty][tx] = local;
    __syncthreads();
    #pragma unroll
    for (int i = 0; i < 4; ++i) {
        int nl = (tid >> 4) + i * 16;
        int cl = (tid & 15) * 4;
        ushort4 u;
        u.x = f2bf(t[cl + 0][nl]);
        u.y = f2bf(t[cl + 1][nl]);
        u.z = f2bf(t[cl + 2][nl]);
        u.w = f2bf(t[cl + 3][nl]);
        *reinterpret_cast<ushort4*>(Xt + ((size_t)b * N_ + n0 + nl) * 512 + c0 + cl) = u;
    }
    if (tid < 64)
        csq1[(size_t)blockIdx.y * NCOL + (size_t)b * N_ + n0 + tid] =
            sq[0][tid] + sq[1][tid] + sq[2][tid] + sq[3][tid];
}

// ---------------------------------------------------------------------------
// reduce 8 csq1 partials -> rs1 = sqrt(512)/max(||x_col||, eps)
// ---------------------------------------------------------------------------
__global__ __launch_bounds__(256) void rs1_reduce_k(const float* __restrict__ csq1,
                                                    float* __restrict__ rs1)
{
    int col = blockIdx.x * 256 + threadIdx.x;
    float s = 0.f;
    #pragma unroll
    for (int j = 0; j < 8; ++j) s += csq1[(size_t)j * NCOL + col];
    rs1[col] = 22.627416998f / fmaxf(sqrtf(s), 1e-12f);
}

// ---------------------------------------------------------------------------
// MFMA GEMM1: acc[o][n] = sum_c A[o][c] * Bt[b][n][c]   (A,Bt bf16, K=512)
// 128x128 tile, 4 waves 2x2, BK=64, global_load_lds + XOR chunk swizzle.
// Epilogue: acc *= rs1[b][n];
//   part 0 (q): softmax over d (in-wave reduce) * 0.125 -> q bf16
//   part 1/2 (k/v): -> bf16 raw
// ---------------------------------------------------------------------------
__global__ __launch_bounds__(256)
void mfma_gemm(const ushort* __restrict__ A, const ushort* __restrict__ Bt,
               const float* __restrict__ rs1,
               ushort* __restrict__ qd, ushort* __restrict__ kd,
               ushort* __restrict__ vd)
{
    __shared__ __align__(16) ushort As[128 * 64];
    __shared__ __align__(16) ushort Bs[128 * 64];
    const int b  = blockIdx.z;
    const int n0 = blockIdx.x * 128;
    const int m0 = blockIdx.y * 128;
    const int tid = threadIdx.x;
    const int w = tid >> 6, l = tid & 63;
    const int wm = w >> 1, wn = w & 1;
    const int lq = l >> 4, lr = l & 15;
    const ushort* Bb = Bt + (size_t)b * N_ * 512;

    f32x4 acc[4][4];
    #pragma unroll
    for (int i = 0; i < 4; ++i)
        #pragma unroll
        for (int j = 0; j < 4; ++j)
            #pragma unroll
            for (int r = 0; r < 4; ++r) acc[i][j][r] = 0.f;

    for (int k0 = 0; k0 < 512; k0 += 64) {
        #pragma unroll
        for (int i = 0; i < 4; ++i) {
            int r  = (w * 4 + i) * 8 + (l >> 3);       // 0..127
            int ch = (l & 7) ^ (r & 7);                // swizzled source chunk
            gload_lds16((const char*)A  + (size_t)(m0 + r) * 1024 + k0 * 2 + ch * 16,
                        (char*)As + (size_t)(w * 4 + i) * 1024);
            gload_lds16((const char*)Bb + (size_t)(n0 + r) * 1024 + k0 * 2 + ch * 16,
                        (char*)Bs + (size_t)(w * 4 + i) * 1024);
        }
        __syncthreads();
        #pragma unroll
        for (int kk = 0; kk < 2; ++kk) {
            bf16x8 af[4], bfr[4];
            #pragma unroll
            for (int mf = 0; mf < 4; ++mf) {
                int ra = wm * 64 + mf * 16 + lr;
                int ch = (kk * 4 + lq) ^ (ra & 7);
                af[mf] = *(const bf16x8*)((const char*)As + ra * 128 + ch * 16);
            }
            #pragma unroll
            for (int nf = 0; nf < 4; ++nf) {
                int rb = wn * 64 + nf * 16 + lr;
                int ch = (kk * 4 + lq) ^ (rb & 7);
                bfr[nf] = *(const bf16x8*)((const char*)Bs + rb * 128 + ch * 16);
            }
            #pragma unroll
            for (int mf = 0; mf < 4; ++mf)
                #pragma unroll
                for (int nf = 0; nf < 4; ++nf)
                    acc[mf][nf] = __builtin_amdgcn_mfma_f32_16x16x32_bf16(
                        af[mf], bfr[nf], acc[mf][nf], 0, 0, 0);
        }
        __syncthreads();
    }

    const int ncol = n0 + wn * 64 + lr;
    const int part = m0 >> 9;                      // block-uniform
    const int mrow = (m0 & 511) + wm * 64;         // wave-uniform row base
    if (part == 0) {
        // q: *rs1, softmax over d (rows of this wave), *0.125, bf16
        const size_t bh = (size_t)b * 8 + (mrow >> 6);
        #pragma unroll
        for (int nf = 0; nf < 4; ++nf) {
            const int n = ncol + nf * 16;
            const float sc = rs1[(size_t)b * N_ + n];
            float v[4][4];
            float mx = -1e30f;
            #pragma unroll
            for (int mf = 0; mf < 4; ++mf)
                #pragma unroll
                for (int r = 0; r < 4; ++r) {
                    v[mf][r] = acc[mf][nf][r] * sc;
                    mx = fmaxf(mx, v[mf][r]);
                }
            mx = fmaxf(mx, __shfl_xor(mx, 16));
            mx = fmaxf(mx, __shfl_xor(mx, 32));
            float s = 0.f;
            #pragma unroll
            for (int mf = 0; mf < 4; ++mf)
                #pragma unroll
                for (int r = 0; r < 4; ++r) {
                    v[mf][r] = __expf(v[mf][r] - mx);
                    s += v[mf][r];
                }
            s += __shfl_xor(s, 16);
            s += __shfl_xor(s, 32);
            const float r8 = 0.125f / s;
            #pragma unroll
            for (int mf = 0; mf < 4; ++mf)
                #pragma unroll
                for (int r = 0; r < 4; ++r)
                    qd[(bh * 64 + mf * 16 + lq * 4 + r) * N_ + n] =
                        f2bf(v[mf][r] * r8);
        }
    } else {
        ushort* dst = (part == 1) ? kd : vd;
        const int mb = mrow + lq * 4;
        #pragma unroll
        for (int nf = 0; nf < 4; ++nf) {
            const int n = ncol + nf * 16;
            const float sc = rs1[(size_t)b * N_ + n];
            #pragma unroll
            for (int mf = 0; mf < 4; ++mf) {
                const int o = mb + mf * 16;
                #pragma unroll
                for (int r = 0; r < 4; ++r)
                    dst[((size_t)b * 512 + o + r) * N_ + n] =
                        f2bf(acc[mf][nf][r] * sc);
            }
        }
    }
}

// ---------------------------------------------------------------------------
// GEMM2 fused: out[b][o][n] = rmsnorm(Wout@at2 + bias) * g2, full column in
// one block. 512 threads = 8 waves; wave w owns rows [w*64,w*64+64), n-tile 128.
// ---------------------------------------------------------------------------
__global__ __launch_bounds__(512, 2)
void gemm2_k(const ushort* __restrict__ A,      // Woutb [512][512] bf16
             const ushort* __restrict__ Bt,     // at2 [b][n][512] bf16
             const float* __restrict__ bias,
             const float* __restrict__ g2,
             float* __restrict__ outp)
{
    __shared__ __align__(16) ushort As[512 * 64];   // 64 KiB
    __shared__ __align__(16) ushort Bs[128 * 64];   // 16 KiB
    const int b  = blockIdx.y;
    const int n0 = blockIdx.x * 128;
    const int tid = threadIdx.x;
    const int w = tid >> 6, l = tid & 63;
    const int lq = l >> 4, lr = l & 15;
    const ushort* Bb = Bt + (size_t)b * N_ * 512;

    f32x4 acc[4][8];
    #pragma unroll
    for (int i = 0; i < 4; ++i)
        #pragma unroll
        for (int j = 0; j < 8; ++j)
            #pragma unroll
            for (int r = 0; r < 4; ++r) acc[i][j][r] = 0.f;

    for (int k0 = 0; k0 < 512; k0 += 64) {
        // stage A: 512 rows x 64c = 4096 16B-chunks, 8 per thread
        #pragma unroll
        for (int i = 0; i < 8; ++i) {
            int base = i * 512 + w * 64;           // wave-uniform chunk base
            int idx = base + l;
            int r = idx >> 3, ch = (idx & 7) ^ (r & 7);
            gload_lds16((const char*)A + (size_t)r * 1024 + k0 * 2 + ch * 16,
                        (char*)As + (size_t)base * 16);
        }
        // stage B: 128 rows x 64c = 1024 chunks, 2 per thread
        #pragma unroll
        for (int i = 0; i < 2; ++i) {
            int base = i * 512 + w * 64;
            int idx = base + l;
            int r = idx >> 3, ch = (idx & 7) ^ (r & 7);
            gload_lds16((const char*)Bb + (size_t)(n0 + r) * 1024 + k0 * 2 + ch * 16,
                        (char*)Bs + (size_t)base * 16);
        }
        __syncthreads();
        #pragma unroll
        for (int kk = 0; kk < 2; ++kk) {
            bf16x8 af[4], bfr[8];
            #pragma unroll
            for (int mf = 0; mf < 4; ++mf) {
                int ra = w * 64 + mf * 16 + lr;
                int ch = (kk * 4 + lq) ^ (ra & 7);
                af[mf] = *(const bf16x8*)((const char*)As + ra * 128 + ch * 16);
            }
            #pragma unroll
            for (int nf = 0; nf < 8; ++nf) {
                int rb = nf * 16 + lr;
                int ch = (kk * 4 + lq) ^ (rb & 7);
                bfr[nf] = *(const bf16x8*)((const char*)Bs + rb * 128 + ch * 16);
            }
            #pragma unroll
            for (int mf = 0; mf < 4; ++mf)
                #pragma unroll
                for (int nf = 0; nf < 8; ++nf)
                    acc[mf][nf] = __builtin_amdgcn_mfma_f32_16x16x32_bf16(
                        af[mf], bfr[nf], acc[mf][nf], 0, 0, 0);
        }
        __syncthreads();
    }

    // epilogue: add bias, accumulate column sumsq, rms-norm, write final f32
    float4 bv[4], g2v[4];
    #pragma unroll
    for (int mf = 0; mf < 4; ++mf) {
        bv[mf]  = *reinterpret_cast<const float4*>(bias + w * 64 + mf * 16 + lq * 4);
        g2v[mf] = *reinterpret_cast<const float4*>(g2   + w * 64 + mf * 16 + lq * 4);
    }
    float csq[8] = {};
    #pragma unroll
    for (int mf = 0; mf < 4; ++mf)
        #pragma unroll
        for (int nf = 0; nf < 8; ++nf)
            #pragma unroll
            for (int r = 0; r < 4; ++r) {
                float wv = acc[mf][nf][r] + ((const float*)&bv[mf])[r];
                acc[mf][nf][r] = wv;
                csq[nf] += wv * wv;
            }
    #pragma unroll
    for (int nf = 0; nf < 8; ++nf) {
        csq[nf] += __shfl_xor(csq[nf], 16);
        csq[nf] += __shfl_xor(csq[nf], 32);
    }
    float* red  = (float*)As;       // 8 x 128 floats
    float* rs2s = red + 1024;       // 128 floats
    if (lq == 0) {
        #pragma unroll
        for (int nf = 0; nf < 8; ++nf)
            red[w * 128 + nf * 16 + lr] = csq[nf];
    }
    __syncthreads();
    if (tid < 128) {
        float s = 0.f;
        #pragma unroll
        for (int j = 0; j < 8; ++j) s += red[j * 128 + tid];
        rs2s[tid] = 22.627416998f / fmaxf(sqrtf(s), 1e-12f);
    }
    __syncthreads();
    #pragma unroll
    for (int nf = 0; nf < 8; ++nf) {
        const float rsv = rs2s[nf * 16 + lr];
        const int n = n0 + nf * 16 + lr;
        #pragma unroll
        for (int mf = 0; mf < 4; ++mf) {
            const int o = w * 64 + mf * 16 + lq * 4;
            float* p = outp + ((size_t)b * 512 + o) * N_ + n;
            #pragma unroll
            for (int r = 0; r < 4; ++r)
                p[(size_t)r * N_] = acc[mf][nf][r] * rsv * ((const float*)&g2v[mf])[r];
        }
    }
}

// ---------------------------------------------------------------------------
// row stats for k-softmax: per row (bh*64+d) of 4096 bf16 scores ->
// rowm = max, rowr = 1/sum(exp(v-max)).  One wave per row.
// ---------------------------------------------------------------------------
__global__ __launch_bounds__(256) void rowstat_k(const ushort* __restrict__ kk,
                                                 float* __restrict__ rowm,
                                                 float* __restrict__ rowr)
{
    const int row = blockIdx.x * 4 + (threadIdx.x >> 6);
    const int lane = threadIdx.x & 63;
    const ushort* p = kk + (size_t)row * N_;
    float vals[64];
    #pragma unroll
    for (int j = 0; j < 8; ++j) {
        ushort8_t u = *reinterpret_cast<const ushort8_t*>(p + lane * 8 + j * 512);
        #pragma unroll
        for (int t = 0; t < 8; ++t) vals[j * 8 + t] = bf2f(u[t]);
    }
    float mx = -1e30f;
    #pragma unroll
    for (int i = 0; i < 64; ++i) mx = fmaxf(mx, vals[i]);
    #pragma unroll
    for (int o = 32; o >= 1; o >>= 1) mx = fmaxf(mx, __shfl_xor(mx, o));
    float s = 0.f;
    #pragma unroll
    for (int i = 0; i < 64; ++i) s += __expf(vals[i] - mx);
    #pragma unroll
    for (int o = 32; o >= 1; o >>= 1) s += __shfl_xor(s, o);
    if (lane == 0) { rowm[row] = mx; rowr[row] = 1.f / s; }
}

// ---------------------------------------------------------------------------
// context partial: ctxp[bh*4+chunk][d][e] =
//   rowr[d] * sum_{n in chunk} exp(k[bh][d][n]-rowm[d]) * v[bh][e][n]
// ---------------------------------------------------------------------------
__global__ __launch_bounds__(256) void ctx_k(const ushort* __restrict__ kk,
                                             const ushort* __restrict__ vv,
                                             const float* __restrict__ rowm,
                                             const float* __restrict__ rowr,
                                             float* __restrict__ ctxp)
{
    const int bh = blockIdx.x, chunk = blockIdx.y;
    const ushort* kp = kk + (size_t)bh * 64 * N_;
    const ushort* vp = vv + (size_t)bh * 64 * N_;
    __shared__ float ks[64][129];
    __shared__ float vs[64][129];
    __shared__ float rm[64];
    const int tid = threadIdx.x;
    if (tid < 64) rm[tid] = rowm[(size_t)bh * 64 + tid];
    __syncthreads();
    const int td = tid >> 4, te = tid & 15;
    float acc[4][4] = {};
    for (int n0 = chunk * 1024; n0 < chunk * 1024 + 1024; n0 += 128) {
        #pragma unroll
        for (int i = 0; i < 32; ++i) {
            int idx = i * 256 + tid;
            int d = idx >> 7, nn = idx & 127;
            ks[d][nn] = __expf(bf2f(kp[(size_t)d * N_ + n0 + nn]) - rm[d]);
            vs[d][nn] = bf2f(vp[(size_t)d * N_ + n0 + nn]);
        }
        __syncthreads();
        for (int nn = 0; nn < 128; ++nn) {
            float a[4], bb[4];
            #pragma unroll
            for (int i = 0; i < 4; ++i) a[i]  = ks[td * 4 + i][nn];
            #pragma unroll
            for (int j = 0; j < 4; ++j) bb[j] = vs[te * 4 + j][nn];
            #pragma unroll
            for (int i = 0; i < 4; ++i)
                #pragma unroll
                for (int j = 0; j < 4; ++j)
                    acc[i][j] = fmaf(a[i], bb[j], acc[i][j]);
        }
        __syncthreads();
    }
    float rrv[4];
    #pragma unroll
    for (int i = 0; i < 4; ++i) rrv[i] = rowr[(size_t)bh * 64 + td * 4 + i];
    #pragma unroll
    for (int i = 0; i < 4; ++i)
        #pragma unroll
        for (int j = 0; j < 4; ++j)
            ctxp[((size_t)bh * 4 + chunk) * 4096 + (td * 4 + i) * 64 + te * 4 + j] =
                acc[i][j] * rrv[i];
}

// ---------------------------------------------------------------------------
// attn: at2[b][n][h*64+e] = bf16( sum_d ctx[bh][d][e] * q[bh][d][n] )
// ---------------------------------------------------------------------------
__global__ __launch_bounds__(256) void attn_k(const float* __restrict__ ctxp,
                                              const ushort* __restrict__ q,
                                              ushort* __restrict__ at2)
{
    const int bh = blockIdx.y;
    const int n0 = blockIdx.x * 256;
    __shared__ __align__(16) float ctx_s[64][64];
    __shared__ __align__(16) float q_s[64][256];
    const float* cp = ctxp + (size_t)bh * 4 * 4096;
    const ushort* qp = q + (size_t)bh * 64 * N_;
    const int tid = threadIdx.x;
    #pragma unroll
    for (int i = 0; i < 16; ++i) {
        int idx = i * 256 + tid;
        ctx_s[idx >> 6][idx & 63] = cp[idx] + cp[idx + 4096] + cp[idx + 8192] + cp[idx + 12288];
    }
    #pragma unroll 4
    for (int d = 0; d < 64; ++d)
        q_s[d][tid] = bf2f(qp[(size_t)d * N_ + n0 + tid]);
    __syncthreads();
    const int eg = tid >> 6;
    const int ng = tid & 63;
    float acc[16][4] = {};
    for (int d = 0; d < 64; ++d) {
        float qv[4];
        *(float4*)qv = *(float4*)&q_s[d][ng * 4];
        float cv[16];
        #pragma unroll
        for (int t = 0; t < 4; ++t)
            *(float4*)&cv[t * 4] = *(float4*)&ctx_s[d][eg * 16 + t * 4];
        #pragma unroll
        for (int e = 0; e < 16; ++e)
            #pragma unroll
            for (int j = 0; j < 4; ++j)
                acc[e][j] = fmaf(cv[e], qv[j], acc[e][j]);
    }
    const int b = bh >> 3, h = bh & 7;
    ushort* op = at2 + ((size_t)b * N_ + n0 + ng * 4) * 512 + h * 64 + eg * 16;
    #pragma unroll
    for (int j = 0; j < 4; ++j) {
        ushort4* pp = (ushort4*)(op + (size_t)j * 512);
        ushort4 u;
        u.x=f2bf(acc[0][j]);  u.y=f2bf(acc[1][j]);  u.z=f2bf(acc[2][j]);  u.w=f2bf(acc[3][j]);  pp[0]=u;
        u.x=f2bf(acc[4][j]);  u.y=f2bf(acc[5][j]);  u.z=f2bf(acc[6][j]);  u.w=f2bf(acc[7][j]);  pp[1]=u;
        u.x=f2bf(acc[8][j]);  u.y=f2bf(acc[9][j]);  u.z=f2bf(acc[10][j]); u.w=f2bf(acc[11][j]); pp[2]=u;
        u.x=f2bf(acc[12][j]); u.y=f2bf(acc[13][j]); u.z=f2bf(acc[14][j]); u.w=f2bf(acc[15][j]); pp[3]=u;
    }
}

// ---------------------------------------------------------------------------
extern "C" void kernel_launch(void* const* d_in, const int* in_sizes, int n_in,
                              void* d_out, int out_size, void* d_ws, size_t ws_size,
                              hipStream_t stream)
{
    const float* x    = (const float*)d_in[0];
    const float* g1   = (const float*)d_in[1];
    const float* Wqkv = (const float*)d_in[2];
    const float* Wout = (const float*)d_in[3];
    const float* bout = (const float*)d_in[4];
    const float* g2   = (const float*)d_in[5];
    float* out = (float*)d_out;

    // ws layout (<= 258.25 MiB):
    //   [0,64Mi)     qbuf bf16        (csq1 f32 2Mi aliased here pre-GEMM1)
    //   [64,128Mi)   kbuf bf16        -> at2 bf16 after ctx_k
    //   [128,192Mi)  vbuf bf16
    //   [192,256Mi)  Xt bf16          -> after GEMM1: ctxp f32 (8Mi) @192,
    //                                    rowm/rowr @200Mi
    //   [256Mi..)    Wqkvb(1.5Mi) Woutb(0.5Mi) rs1(256Ki)
    char* wsb = (char*)d_ws;
    ushort* qbuf  = (ushort*)wsb;
    float*  csq1  = (float*)wsb;     // alias (dead once rs1 computed)
    ushort* kbuf  = (ushort*)(wsb + ((size_t)64 << 20));
    ushort* vbuf  = (ushort*)(wsb + ((size_t)128 << 20));
    ushort* Xt    = (ushort*)(wsb + ((size_t)192 << 20));
    float*  ctxp  = (float*)Xt;
    float*  rowm  = (float*)(wsb + ((size_t)200 << 20));
    float*  rowr  = rowm + 8192;
    char*   tail  = wsb + ((size_t)256 << 20);
    ushort* Wqkvb = (ushort*)tail;
    ushort* Woutb = (ushort*)(tail + (size_t)1536 * 512 * 2);
    float*  rs1   = (float*)(tail + (size_t)1536 * 512 * 2 + (size_t)512 * 512 * 2);
    ushort* at2   = kbuf;   // alias: k dead after ctx_k

    // 1. weight prep (bf16; g1 folded into Wqkv)
    wprep_k<<<768, 256, 0, stream>>>(Wqkv, g1, Wqkvb, 1536 * 512 / 4);
    wprep_k<<<256, 256, 0, stream>>>(Wout, nullptr, Woutb, 512 * 512 / 4);
    // 2. Xt[b][n][c] = bf16(x^T) + column sumsq partials
    transpose_k<<<dim3(64, 8, 16), 256, 0, stream>>>(x, Xt, csq1);
    // 3. rs1 = sqrt(512)/||x_col||
    rs1_reduce_k<<<256, 256, 0, stream>>>(csq1, rs1);
    // 4. QKV GEMM: q(softmaxed, bf16), k(raw bf16), v(bf16)
    mfma_gemm<<<dim3(32, 12, B_), 256, 0, stream>>>(Wqkvb, Xt, rs1,
                                                    qbuf, kbuf, vbuf);
    // 5. k row stats (max, 1/sum-exp)
    rowstat_k<<<2048, 256, 0, stream>>>(kbuf, rowm, rowr);
    // 6. context partials (softmax applied on the fly)
    ctx_k<<<dim3(B_ * 8, 4), 256, 0, stream>>>(kbuf, vbuf, rowm, rowr, ctxp);
    // 7. attn -> at2 bf16 [b][n][hid]
    attn_k<<<dim3(N_ / 256, B_ * 8), 256, 0, stream>>>(ctxp, qbuf, at2);
    // 8. output GEMM + bias + full rms-norm fused -> d_out f32 (final)
    gemm2_k<<<dim3(32, B_), 512, 0, stream>>>(Woutb, at2, bout, g2, out);
}

// Round 5
// 438.081 us; speedup vs baseline: 4.7947x; 1.0403x over previous
//
#include <hip/hip_runtime.h>
#include <hip/hip_bf16.h>
#include <math.h>

#define B_ 16
#define C_ 512
#define N_ 4096
#define NCOL (B_ * N_)  // 65536 columns (b, hw)

typedef short bf16x8 __attribute__((ext_vector_type(8)));
typedef ushort ushort8_t __attribute__((ext_vector_type(8)));
typedef float f32x4 __attribute__((ext_vector_type(4)));

__device__ __forceinline__ ushort f2bf(float f) {
    unsigned u = __float_as_uint(f);
    unsigned r = (u + 0x7FFFu + ((u >> 16) & 1u)) >> 16;
    return (ushort)r;
}
__device__ __forceinline__ float bf2f(ushort u) {
    return __uint_as_float((unsigned)u << 16);
}
__device__ __forceinline__ void gload_lds16(const void* g, void* l) {
    __builtin_amdgcn_global_load_lds(
        (const __attribute__((address_space(1))) unsigned int*)g,
        (__attribute__((address_space(3))) unsigned int*)l, 16, 0, 0);
}

// ---------------------------------------------------------------------------
// weight prep: Wb[i] = bf16(W[i] * g[c])  (g optional, c = flat%512)
// ---------------------------------------------------------------------------
__global__ __launch_bounds__(256) void wprep_k(const float* __restrict__ W,
                                               const float* __restrict__ g,
                                               ushort* __restrict__ Wb, int nvec)
{
    int i = blockIdx.x * 256 + threadIdx.x;
    if (i >= nvec) return;
    float4 wv = reinterpret_cast<const float4*>(W)[i];
    if (g) {
        const float4 gv = *reinterpret_cast<const float4*>(g + ((i * 4) & 511));
        wv.x *= gv.x; wv.y *= gv.y; wv.z *= gv.z; wv.w *= gv.w;
    }
    ushort4 u;
    u.x = f2bf(wv.x); u.y = f2bf(wv.y); u.z = f2bf(wv.z); u.w = f2bf(wv.w);
    reinterpret_cast<ushort4*>(Wb)[i] = u;
}

// ---------------------------------------------------------------------------
// transpose+convert+colnorm-partial:
//   Xt[b][n][c] = bf16(x[b][c][n]);  csq1[ctile][b*4096+n] += sum_c x^2
// ---------------------------------------------------------------------------
__global__ __launch_bounds__(256) void transpose_k(const float* __restrict__ X,
                                                   ushort* __restrict__ Xt,
                                                   float* __restrict__ csq1)
{
    __shared__ float t[64][65];
    __shared__ float sq[4][64];
    const int b = blockIdx.z, n0 = blockIdx.x * 64, c0 = blockIdx.y * 64;
    const int tid = threadIdx.x;
    const int tx = tid & 63, ty = tid >> 6;
    const float* xp = X + ((size_t)b * C_ + c0) * N_ + n0;
    float local = 0.f;
    #pragma unroll
    for (int i = 0; i < 16; ++i) {
        float v = xp[(size_t)(ty + 4 * i) * N_ + tx];
        t[ty + 4 * i][tx] = v;
        local += v * v;
    }
    sq[ty][tx] = local;
    __syncthreads();
    #pragma unroll
    for (int i = 0; i < 4; ++i) {
        int nl = (tid >> 4) + i * 16;
        int cl = (tid & 15) * 4;
        ushort4 u;
        u.x = f2bf(t[cl + 0][nl]);
        u.y = f2bf(t[cl + 1][nl]);
        u.z = f2bf(t[cl + 2][nl]);
        u.w = f2bf(t[cl + 3][nl]);
        *reinterpret_cast<ushort4*>(Xt + ((size_t)b * N_ + n0 + nl) * 512 + c0 + cl) = u;
    }
    if (tid < 64)
        csq1[(size_t)blockIdx.y * NCOL + (size_t)b * N_ + n0 + tid] =
            sq[0][tid] + sq[1][tid] + sq[2][tid] + sq[3][tid];
}

// ---------------------------------------------------------------------------
// reduce 8 csq1 partials -> rs1 = sqrt(512)/max(||x_col||, eps)
// ---------------------------------------------------------------------------
__global__ __launch_bounds__(256) void rs1_reduce_k(const float* __restrict__ csq1,
                                                    float* __restrict__ rs1)
{
    int col = blockIdx.x * 256 + threadIdx.x;
    float s = 0.f;
    #pragma unroll
    for (int j = 0; j < 8; ++j) s += csq1[(size_t)j * NCOL + col];
    rs1[col] = 22.627416998f / fmaxf(sqrtf(s), 1e-12f);
}

// ---------------------------------------------------------------------------
// MFMA GEMM1 (256x256 tile, 8 waves 2x4, BK=64, double-buffered LDS,
// counted-vmcnt pipeline):  acc[o][n] = sum_c A[o][c] * Bt[b][n][c]
// Epilogue: acc *= rs1[b][n];
//   part 0 (q): softmax over d (in-wave reduce) * 0.125 -> q bf16
//   part 1/2 (k/v): -> bf16 raw
// ---------------------------------------------------------------------------
__global__ __launch_bounds__(512, 2)
void mfma_gemm(const ushort* __restrict__ A, const ushort* __restrict__ Bt,
               const float* __restrict__ rs1,
               ushort* __restrict__ qd, ushort* __restrict__ kd,
               ushort* __restrict__ vd)
{
    // lds[buf][A/B][256 rows][8 chunks][16B]
    __shared__ __align__(16) char lds[2][2][32768];
    const int b  = blockIdx.z;
    const int n0 = blockIdx.x * 256;
    const int m0 = blockIdx.y * 256;
    const int tid = threadIdx.x;
    const int w = tid >> 6, l = tid & 63;
    const int wm = w >> 2, wn = w & 3;          // 2 x 4 waves
    const int lq = l >> 4, lr = l & 15;
    const ushort* Bb = Bt + (size_t)b * N_ * 512;

    f32x4 acc[8][4];
    #pragma unroll
    for (int i = 0; i < 8; ++i)
        #pragma unroll
        for (int j = 0; j < 4; ++j)
            #pragma unroll
            for (int r = 0; r < 4; ++r) acc[i][j][r] = 0.f;

    // staging: 256 rows x 8 chunks of 16B each for A and B; 4 (chunk-pairs)
    // per thread; source chunk pre-swizzled (ch ^= row&7), dest linear.
#define STAGE_TILE(t, dbuf)                                                   \
    {                                                                         \
        const int kb = (t) * 128;                                             \
        _Pragma("unroll")                                                     \
        for (int i = 0; i < 4; ++i) {                                         \
            int idx = i * 512 + tid;                                          \
            int r = idx >> 3;                                                 \
            int ch = (idx & 7) ^ (r & 7);                                     \
            gload_lds16((const char*)A + (size_t)(m0 + r) * 1024 + kb + ch * 16, \
                        &lds[dbuf][0][idx * 16]);                             \
            gload_lds16((const char*)Bb + (size_t)(n0 + r) * 1024 + kb + ch * 16,\
                        &lds[dbuf][1][idx * 16]);                             \
        }                                                                     \
    }

    STAGE_TILE(0, 0);

    for (int t = 0; t < 8; ++t) {
        const int cur = t & 1;
        if (t < 7) {
            STAGE_TILE(t + 1, cur ^ 1);
            asm volatile("s_waitcnt vmcnt(8)" ::: "memory");   // stage(t) done
        } else {
            asm volatile("s_waitcnt vmcnt(0)" ::: "memory");
        }
        __builtin_amdgcn_s_barrier();
        asm volatile("" ::: "memory");
        const char* As = lds[cur][0];
        const char* Bs = lds[cur][1];
        #pragma unroll
        for (int kk = 0; kk < 2; ++kk) {
            bf16x8 af[8], bfr[4];
            #pragma unroll
            for (int mf = 0; mf < 8; ++mf) {
                int ra = wm * 128 + mf * 16 + lr;
                int ch = (kk * 4 + lq) ^ (ra & 7);
                af[mf] = *(const bf16x8*)(As + ra * 128 + ch * 16);
            }
            #pragma unroll
            for (int nf = 0; nf < 4; ++nf) {
                int rb = wn * 64 + nf * 16 + lr;
                int ch = (kk * 4 + lq) ^ (rb & 7);
                bfr[nf] = *(const bf16x8*)(Bs + rb * 128 + ch * 16);
            }
            __builtin_amdgcn_s_setprio(1);
            #pragma unroll
            for (int mf = 0; mf < 8; ++mf)
                #pragma unroll
                for (int nf = 0; nf < 4; ++nf)
                    acc[mf][nf] = __builtin_amdgcn_mfma_f32_16x16x32_bf16(
                        af[mf], bfr[nf], acc[mf][nf], 0, 0, 0);
            __builtin_amdgcn_s_setprio(0);
        }
        __builtin_amdgcn_s_barrier();
        asm volatile("" ::: "memory");
    }
#undef STAGE_TILE

    const int part = m0 >> 9;                       // block-uniform (0/1/2)
    const int mloc = (m0 & 511) + wm * 128;         // 0/128/256/384 within part
    const int nbase = n0 + wn * 64;
    if (part == 0) {
        // q: *rs1, softmax over the 64 d-rows of each head, *0.125, bf16.
        // wave holds 2 heads: hg=0 -> mf 0..3, hg=1 -> mf 4..7.
        #pragma unroll
        for (int hg = 0; hg < 2; ++hg) {
            const int head = (mloc >> 6) + hg;
            const size_t qrow = ((size_t)b * 8 + head) * 64;
            #pragma unroll
            for (int nf = 0; nf < 4; ++nf) {
                const int n = nbase + nf * 16 + lr;
                const float sc = rs1[(size_t)b * N_ + n];
                float v[4][4];
                float mx = -1e30f;
                #pragma unroll
                for (int m2 = 0; m2 < 4; ++m2)
                    #pragma unroll
                    for (int r = 0; r < 4; ++r) {
                        v[m2][r] = acc[hg * 4 + m2][nf][r] * sc;
                        mx = fmaxf(mx, v[m2][r]);
                    }
                mx = fmaxf(mx, __shfl_xor(mx, 16));
                mx = fmaxf(mx, __shfl_xor(mx, 32));
                float s = 0.f;
                #pragma unroll
                for (int m2 = 0; m2 < 4; ++m2)
                    #pragma unroll
                    for (int r = 0; r < 4; ++r) {
                        v[m2][r] = __expf(v[m2][r] - mx);
                        s += v[m2][r];
                    }
                s += __shfl_xor(s, 16);
                s += __shfl_xor(s, 32);
                const float r8 = 0.125f / s;
                #pragma unroll
                for (int m2 = 0; m2 < 4; ++m2)
                    #pragma unroll
                    for (int r = 0; r < 4; ++r)
                        qd[(qrow + m2 * 16 + lq * 4 + r) * N_ + n] =
                            f2bf(v[m2][r] * r8);
            }
        }
    } else {
        ushort* dst = (part == 1) ? kd : vd;
        #pragma unroll
        for (int nf = 0; nf < 4; ++nf) {
            const int n = nbase + nf * 16 + lr;
            const float sc = rs1[(size_t)b * N_ + n];
            #pragma unroll
            for (int mf = 0; mf < 8; ++mf) {
                const int o = mloc + mf * 16 + lq * 4;
                #pragma unroll
                for (int r = 0; r < 4; ++r)
                    dst[((size_t)b * 512 + o + r) * N_ + n] =
                        f2bf(acc[mf][nf][r] * sc);
            }
        }
    }
}

// ---------------------------------------------------------------------------
// GEMM2 fused: out[b][o][n] = rmsnorm(Wout@at2 + bias) * g2, full column in
// one block. 512 threads = 8 waves; wave w owns rows [w*64,w*64+64), n-tile 128.
// ---------------------------------------------------------------------------
__global__ __launch_bounds__(512, 2)
void gemm2_k(const ushort* __restrict__ A,      // Woutb [512][512] bf16
             const ushort* __restrict__ Bt,     // at2 [b][n][512] bf16
             const float* __restrict__ bias,
             const float* __restrict__ g2,
             float* __restrict__ outp)
{
    __shared__ __align__(16) ushort As[512 * 64];   // 64 KiB
    __shared__ __align__(16) ushort Bs[128 * 64];   // 16 KiB
    const int b  = blockIdx.y;
    const int n0 = blockIdx.x * 128;
    const int tid = threadIdx.x;
    const int w = tid >> 6, l = tid & 63;
    const int lq = l >> 4, lr = l & 15;
    const ushort* Bb = Bt + (size_t)b * N_ * 512;

    f32x4 acc[4][8];
    #pragma unroll
    for (int i = 0; i < 4; ++i)
        #pragma unroll
        for (int j = 0; j < 8; ++j)
            #pragma unroll
            for (int r = 0; r < 4; ++r) acc[i][j][r] = 0.f;

    for (int k0 = 0; k0 < 512; k0 += 64) {
        #pragma unroll
        for (int i = 0; i < 8; ++i) {
            int base = i * 512 + w * 64;           // wave-uniform chunk base
            int idx = base + l;
            int r = idx >> 3, ch = (idx & 7) ^ (r & 7);
            gload_lds16((const char*)A + (size_t)r * 1024 + k0 * 2 + ch * 16,
                        (char*)As + (size_t)base * 16);
        }
        #pragma unroll
        for (int i = 0; i < 2; ++i) {
            int base = i * 512 + w * 64;
            int idx = base + l;
            int r = idx >> 3, ch = (idx & 7) ^ (r & 7);
            gload_lds16((const char*)Bb + (size_t)(n0 + r) * 1024 + k0 * 2 + ch * 16,
                        (char*)Bs + (size_t)base * 16);
        }
        __syncthreads();
        #pragma unroll
        for (int kk = 0; kk < 2; ++kk) {
            bf16x8 af[4], bfr[8];
            #pragma unroll
            for (int mf = 0; mf < 4; ++mf) {
                int ra = w * 64 + mf * 16 + lr;
                int ch = (kk * 4 + lq) ^ (ra & 7);
                af[mf] = *(const bf16x8*)((const char*)As + ra * 128 + ch * 16);
            }
            #pragma unroll
            for (int nf = 0; nf < 8; ++nf) {
                int rb = nf * 16 + lr;
                int ch = (kk * 4 + lq) ^ (rb & 7);
                bfr[nf] = *(const bf16x8*)((const char*)Bs + rb * 128 + ch * 16);
            }
            #pragma unroll
            for (int mf = 0; mf < 4; ++mf)
                #pragma unroll
                for (int nf = 0; nf < 8; ++nf)
                    acc[mf][nf] = __builtin_amdgcn_mfma_f32_16x16x32_bf16(
                        af[mf], bfr[nf], acc[mf][nf], 0, 0, 0);
        }
        __syncthreads();
    }

    // epilogue: add bias, accumulate column sumsq, rms-norm, write final f32
    float4 bv[4], g2v[4];
    #pragma unroll
    for (int mf = 0; mf < 4; ++mf) {
        bv[mf]  = *reinterpret_cast<const float4*>(bias + w * 64 + mf * 16 + lq * 4);
        g2v[mf] = *reinterpret_cast<const float4*>(g2   + w * 64 + mf * 16 + lq * 4);
    }
    float csq[8] = {};
    #pragma unroll
    for (int mf = 0; mf < 4; ++mf)
        #pragma unroll
        for (int nf = 0; nf < 8; ++nf)
            #pragma unroll
            for (int r = 0; r < 4; ++r) {
                float wv = acc[mf][nf][r] + ((const float*)&bv[mf])[r];
                acc[mf][nf][r] = wv;
                csq[nf] += wv * wv;
            }
    #pragma unroll
    for (int nf = 0; nf < 8; ++nf) {
        csq[nf] += __shfl_xor(csq[nf], 16);
        csq[nf] += __shfl_xor(csq[nf], 32);
    }
    float* red  = (float*)As;       // 8 x 128 floats
    float* rs2s = red + 1024;       // 128 floats
    if (lq == 0) {
        #pragma unroll
        for (int nf = 0; nf < 8; ++nf)
            red[w * 128 + nf * 16 + lr] = csq[nf];
    }
    __syncthreads();
    if (tid < 128) {
        float s = 0.f;
        #pragma unroll
        for (int j = 0; j < 8; ++j) s += red[j * 128 + tid];
        rs2s[tid] = 22.627416998f / fmaxf(sqrtf(s), 1e-12f);
    }
    __syncthreads();
    #pragma unroll
    for (int nf = 0; nf < 8; ++nf) {
        const float rsv = rs2s[nf * 16 + lr];
        const int n = n0 + nf * 16 + lr;
        #pragma unroll
        for (int mf = 0; mf < 4; ++mf) {
            const int o = w * 64 + mf * 16 + lq * 4;
            float* p = outp + ((size_t)b * 512 + o) * N_ + n;
            #pragma unroll
            for (int r = 0; r < 4; ++r)
                p[(size_t)r * N_] = acc[mf][nf][r] * rsv * ((const float*)&g2v[mf])[r];
        }
    }
}

// ---------------------------------------------------------------------------
// row stats for k-softmax: per row (bh*64+d) of 4096 bf16 scores ->
// rowm = max, rowr = 1/sum(exp(v-max)).  One wave per row.
// ---------------------------------------------------------------------------
__global__ __launch_bounds__(256) void rowstat_k(const ushort* __restrict__ kk,
                                                 float* __restrict__ rowm,
                                                 float* __restrict__ rowr)
{
    const int row = blockIdx.x * 4 + (threadIdx.x >> 6);
    const int lane = threadIdx.x & 63;
    const ushort* p = kk + (size_t)row * N_;
    float vals[64];
    #pragma unroll
    for (int j = 0; j < 8; ++j) {
        ushort8_t u = *reinterpret_cast<const ushort8_t*>(p + lane * 8 + j * 512);
        #pragma unroll
        for (int t = 0; t < 8; ++t) vals[j * 8 + t] = bf2f(u[t]);
    }
    float mx = -1e30f;
    #pragma unroll
    for (int i = 0; i < 64; ++i) mx = fmaxf(mx, vals[i]);
    #pragma unroll
    for (int o = 32; o >= 1; o >>= 1) mx = fmaxf(mx, __shfl_xor(mx, o));
    float s = 0.f;
    #pragma unroll
    for (int i = 0; i < 64; ++i) s += __expf(vals[i] - mx);
    #pragma unroll
    for (int o = 32; o >= 1; o >>= 1) s += __shfl_xor(s, o);
    if (lane == 0) { rowm[row] = mx; rowr[row] = 1.f / s; }
}

// ---------------------------------------------------------------------------
// context partial: ctxp[bh*4+chunk][d][e] =
//   rowr[d] * sum_{n in chunk} exp(k[bh][d][n]-rowm[d]) * v[bh][e][n]
// ---------------------------------------------------------------------------
__global__ __launch_bounds__(256) void ctx_k(const ushort* __restrict__ kk,
                                             const ushort* __restrict__ vv,
                                             const float* __restrict__ rowm,
                                             const float* __restrict__ rowr,
                                             float* __restrict__ ctxp)
{
    const int bh = blockIdx.x, chunk = blockIdx.y;
    const ushort* kp = kk + (size_t)bh * 64 * N_;
    const ushort* vp = vv + (size_t)bh * 64 * N_;
    __shared__ float ks[64][129];
    __shared__ float vs[64][129];
    __shared__ float rm[64];
    const int tid = threadIdx.x;
    if (tid < 64) rm[tid] = rowm[(size_t)bh * 64 + tid];
    __syncthreads();
    const int td = tid >> 4, te = tid & 15;
    float acc[4][4] = {};
    for (int n0 = chunk * 1024; n0 < chunk * 1024 + 1024; n0 += 128) {
        #pragma unroll
        for (int i = 0; i < 32; ++i) {
            int idx = i * 256 + tid;
            int d = idx >> 7, nn = idx & 127;
            ks[d][nn] = __expf(bf2f(kp[(size_t)d * N_ + n0 + nn]) - rm[d]);
            vs[d][nn] = bf2f(vp[(size_t)d * N_ + n0 + nn]);
        }
        __syncthreads();
        for (int nn = 0; nn < 128; ++nn) {
            float a[4], bb[4];
            #pragma unroll
            for (int i = 0; i < 4; ++i) a[i]  = ks[td * 4 + i][nn];
            #pragma unroll
            for (int j = 0; j < 4; ++j) bb[j] = vs[te * 4 + j][nn];
            #pragma unroll
            for (int i = 0; i < 4; ++i)
                #pragma unroll
                for (int j = 0; j < 4; ++j)
                    acc[i][j] = fmaf(a[i], bb[j], acc[i][j]);
        }
        __syncthreads();
    }
    float rrv[4];
    #pragma unroll
    for (int i = 0; i < 4; ++i) rrv[i] = rowr[(size_t)bh * 64 + td * 4 + i];
    #pragma unroll
    for (int i = 0; i < 4; ++i)
        #pragma unroll
        for (int j = 0; j < 4; ++j)
            ctxp[((size_t)bh * 4 + chunk) * 4096 + (td * 4 + i) * 64 + te * 4 + j] =
                acc[i][j] * rrv[i];
}

// ---------------------------------------------------------------------------
// attn: at2[b][n][h*64+e] = bf16( sum_d ctx[bh][d][e] * q[bh][d][n] )
// ---------------------------------------------------------------------------
__global__ __launch_bounds__(256) void attn_k(const float* __restrict__ ctxp,
                                              const ushort* __restrict__ q,
                                              ushort* __restrict__ at2)
{
    const int bh = blockIdx.y;
    const int n0 = blockIdx.x * 256;
    __shared__ __align__(16) float ctx_s[64][64];
    __shared__ __align__(16) float q_s[64][256];
    const float* cp = ctxp + (size_t)bh * 4 * 4096;
    const ushort* qp = q + (size_t)bh * 64 * N_;
    const int tid = threadIdx.x;
    #pragma unroll
    for (int i = 0; i < 16; ++i) {
        int idx = i * 256 + tid;
        ctx_s[idx >> 6][idx & 63] = cp[idx] + cp[idx + 4096] + cp[idx + 8192] + cp[idx + 12288];
    }
    #pragma unroll 4
    for (int d = 0; d < 64; ++d)
        q_s[d][tid] = bf2f(qp[(size_t)d * N_ + n0 + tid]);
    __syncthreads();
    const int eg = tid >> 6;
    const int ng = tid & 63;
    float acc[16][4] = {};
    for (int d = 0; d < 64; ++d) {
        float qv[4];
        *(float4*)qv = *(float4*)&q_s[d][ng * 4];
        float cv[16];
        #pragma unroll
        for (int t = 0; t < 4; ++t)
            *(float4*)&cv[t * 4] = *(float4*)&ctx_s[d][eg * 16 + t * 4];
        #pragma unroll
        for (int e = 0; e < 16; ++e)
            #pragma unroll
            for (int j = 0; j < 4; ++j)
                acc[e][j] = fmaf(cv[e], qv[j], acc[e][j]);
    }
    const int b = bh >> 3, h = bh & 7;
    ushort* op = at2 + ((size_t)b * N_ + n0 + ng * 4) * 512 + h * 64 + eg * 16;
    #pragma unroll
    for (int j = 0; j < 4; ++j) {
        ushort4* pp = (ushort4*)(op + (size_t)j * 512);
        ushort4 u;
        u.x=f2bf(acc[0][j]);  u.y=f2bf(acc[1][j]);  u.z=f2bf(acc[2][j]);  u.w=f2bf(acc[3][j]);  pp[0]=u;
        u.x=f2bf(acc[4][j]);  u.y=f2bf(acc[5][j]);  u.z=f2bf(acc[6][j]);  u.w=f2bf(acc[7][j]);  pp[1]=u;
        u.x=f2bf(acc[8][j]);  u.y=f2bf(acc[9][j]);  u.z=f2bf(acc[10][j]); u.w=f2bf(acc[11][j]); pp[2]=u;
        u.x=f2bf(acc[12][j]); u.y=f2bf(acc[13][j]); u.z=f2bf(acc[14][j]); u.w=f2bf(acc[15][j]); pp[3]=u;
    }
}

// ---------------------------------------------------------------------------
extern "C" void kernel_launch(void* const* d_in, const int* in_sizes, int n_in,
                              void* d_out, int out_size, void* d_ws, size_t ws_size,
                              hipStream_t stream)
{
    const float* x    = (const float*)d_in[0];
    const float* g1   = (const float*)d_in[1];
    const float* Wqkv = (const float*)d_in[2];
    const float* Wout = (const float*)d_in[3];
    const float* bout = (const float*)d_in[4];
    const float* g2   = (const float*)d_in[5];
    float* out = (float*)d_out;

    // ws layout (<= 258.25 MiB):
    //   [0,64Mi)     qbuf bf16        (csq1 f32 2Mi aliased here pre-GEMM1)
    //   [64,128Mi)   kbuf bf16        -> at2 bf16 after ctx_k
    //   [128,192Mi)  vbuf bf16
    //   [192,256Mi)  Xt bf16          -> after GEMM1: ctxp f32 (8Mi) @192,
    //                                    rowm/rowr @200Mi
    //   [256Mi..)    Wqkvb(1.5Mi) Woutb(0.5Mi) rs1(256Ki)
    char* wsb = (char*)d_ws;
    ushort* qbuf  = (ushort*)wsb;
    float*  csq1  = (float*)wsb;     // alias (dead once rs1 computed)
    ushort* kbuf  = (ushort*)(wsb + ((size_t)64 << 20));
    ushort* vbuf  = (ushort*)(wsb + ((size_t)128 << 20));
    ushort* Xt    = (ushort*)(wsb + ((size_t)192 << 20));
    float*  ctxp  = (float*)Xt;
    float*  rowm  = (float*)(wsb + ((size_t)200 << 20));
    float*  rowr  = rowm + 8192;
    char*   tail  = wsb + ((size_t)256 << 20);
    ushort* Wqkvb = (ushort*)tail;
    ushort* Woutb = (ushort*)(tail + (size_t)1536 * 512 * 2);
    float*  rs1   = (float*)(tail + (size_t)1536 * 512 * 2 + (size_t)512 * 512 * 2);
    ushort* at2   = kbuf;   // alias: k dead after ctx_k

    // 1. weight prep (bf16; g1 folded into Wqkv)
    wprep_k<<<768, 256, 0, stream>>>(Wqkv, g1, Wqkvb, 1536 * 512 / 4);
    wprep_k<<<256, 256, 0, stream>>>(Wout, nullptr, Woutb, 512 * 512 / 4);
    // 2. Xt[b][n][c] = bf16(x^T) + column sumsq partials
    transpose_k<<<dim3(64, 8, 16), 256, 0, stream>>>(x, Xt, csq1);
    // 3. rs1 = sqrt(512)/||x_col||
    rs1_reduce_k<<<256, 256, 0, stream>>>(csq1, rs1);
    // 4. QKV GEMM (256x256, pipelined): q(softmaxed), k, v  (all bf16)
    mfma_gemm<<<dim3(16, 6, B_), 512, 0, stream>>>(Wqkvb, Xt, rs1,
                                                   qbuf, kbuf, vbuf);
    // 5. k row stats (max, 1/sum-exp)
    rowstat_k<<<2048, 256, 0, stream>>>(kbuf, rowm, rowr);
    // 6. context partials (softmax applied on the fly)
    ctx_k<<<dim3(B_ * 8, 4), 256, 0, stream>>>(kbuf, vbuf, rowm, rowr, ctxp);
    // 7. attn -> at2 bf16 [b][n][hid]
    attn_k<<<dim3(N_ / 256, B_ * 8), 256, 0, stream>>>(ctxp, qbuf, at2);
    // 8. output GEMM + bias + full rms-norm fused -> d_out f32 (final)
    gemm2_k<<<dim3(32, B_), 512, 0, stream>>>(Woutb, at2, bout, g2, out);
}